// Round 1
// baseline (1022.388 us; speedup 1.0000x reference)
//
#include <hip/hip_runtime.h>

#define NHEADS 12
#define HDIM 128
#define MODEL_DIM 1536
#define MAX_ATTN_W 13200

typedef unsigned short u16;
typedef unsigned int u32;
typedef float f32x4 __attribute__((ext_vector_type(4)));
typedef __bf16 bf16x8 __attribute__((ext_vector_type(8)));

static __device__ __forceinline__ u16 f2bf(float f) {
  union { __bf16 h; u16 u; } cv;
  cv.h = (__bf16)f;
  return cv.u;
}

// ---------------- fp32 -> bf16 convert ----------------
__global__ void k_conv_bf16(const float* __restrict__ src, u16* __restrict__ dst, int n4) {
  int i = blockIdx.x * blockDim.x + threadIdx.x;
  if (i >= n4) return;
  float4 v = ((const float4*)src)[i];
  u32 lo = (u32)f2bf(v.x) | ((u32)f2bf(v.y) << 16);
  u32 hi = (u32)f2bf(v.z) | ((u32)f2bf(v.w) << 16);
  ((uint2*)dst)[i] = make_uint2(lo, hi);
}

// ---------------- old cache -> bf16 K window [n][jj][d] ----------------
__global__ void k_build_kold(const float* __restrict__ kc, u16* __restrict__ K_all,
                             const int* __restrict__ csp, int S, int KVcap) {
  const int cs = csp[0];
  const int ce = cs + S;
  int wst = ce - MAX_ATTN_W; if (wst < 0) wst = 0;
  const int oldlen = cs - wst;
  const long per = (long)oldlen * 16;   // 16 chunks of 8 along d
  const long total = per * NHEADS;
  for (long c = blockIdx.x * (long)blockDim.x + threadIdx.x; c < total;
       c += (long)gridDim.x * blockDim.x) {
    int n = (int)(c / per);
    long r = c - (long)n * per;
    int jo = (int)(r >> 4);
    int dc = ((int)r & 15) * 8;
    const float* s = kc + ((size_t)(wst + jo) * NHEADS + n) * HDIM + dc;
    float4 a = *(const float4*)s;
    float4 b = *(const float4*)(s + 4);
    uint4 o;
    o.x = (u32)f2bf(a.x) | ((u32)f2bf(a.y) << 16);
    o.y = (u32)f2bf(a.z) | ((u32)f2bf(a.w) << 16);
    o.z = (u32)f2bf(b.x) | ((u32)f2bf(b.y) << 16);
    o.w = (u32)f2bf(b.z) | ((u32)f2bf(b.w) << 16);
    *(uint4*)(K_all + ((size_t)n * KVcap + jo) * HDIM + dc) = o;
  }
}

// ---------------- old cache -> bf16 V^T window [n][d][jj] ----------------
__global__ void k_build_vtold(const float* __restrict__ vc, u16* __restrict__ VT,
                              const int* __restrict__ csp, int S, int KVcap) {
  const int cs = csp[0];
  const int ce = cs + S;
  int wst = ce - MAX_ATTN_W; if (wst < 0) wst = 0;
  const int oldlen = cs - wst;
  const int nj8 = (oldlen + 7) >> 3;
  const long per = (long)HDIM * nj8;
  const long total = per * NHEADS;
  for (long c = blockIdx.x * (long)blockDim.x + threadIdx.x; c < total;
       c += (long)gridDim.x * blockDim.x) {
    int n = (int)(c / per);
    long r = c - (long)n * per;
    int d = (int)(r / nj8);
    int jc = (int)(r - (long)d * nj8);
    int jbase = jc * 8;
    int cnt = oldlen - jbase; if (cnt > 8) cnt = 8;
    u16* dst = VT + ((size_t)n * HDIM + d) * KVcap + jbase;
    if (cnt == 8) {
      u32 words[4];
      #pragma unroll
      for (int i2 = 0; i2 < 4; i2++) {
        float e0 = vc[((size_t)(wst + jbase + 2 * i2) * NHEADS + n) * HDIM + d];
        float e1 = vc[((size_t)(wst + jbase + 2 * i2 + 1) * NHEADS + n) * HDIM + d];
        words[i2] = (u32)f2bf(e0) | ((u32)f2bf(e1) << 16);
      }
      *(uint4*)dst = make_uint4(words[0], words[1], words[2], words[3]);
    } else {
      for (int i = 0; i < cnt; i++)
        dst[i] = f2bf(vc[((size_t)(wst + jbase + i) * NHEADS + n) * HDIM + d]);
    }
  }
}

// ---------------- bf16 GEMM: out[m][n] = sum_k A[m][k]*B[n][k] + bias[n] ----------------
__launch_bounds__(256)
__global__ void k_gemm_bt(const u16* __restrict__ A, const u16* __restrict__ B,
                          const float* __restrict__ bias, float* __restrict__ out,
                          int M, int N, int K) {
  __shared__ __align__(16) u16 Al[64][40];
  __shared__ __align__(16) u16 Bl[64][40];
  const int tid = threadIdx.x;
  const int w = tid >> 6, l = tid & 63, l15 = l & 15, g = l >> 4;
  const int wr = w >> 1, wc = w & 1;
  const int m0 = blockIdx.x * 64, n0 = blockIdx.y * 64;
  f32x4 acc[2][2] = {};
  const int row = tid >> 2, colc = (tid & 3) * 8;
  for (int k0 = 0; k0 < K; k0 += 32) {
    __syncthreads();
    uint4 av = make_uint4(0, 0, 0, 0);
    int gm = m0 + row;
    if (gm < M) av = *(const uint4*)(A + (size_t)gm * K + k0 + colc);
    *(uint4*)&Al[row][colc] = av;
    uint4 bv = *(const uint4*)(B + (size_t)(n0 + row) * K + k0 + colc);
    *(uint4*)&Bl[row][colc] = bv;
    __syncthreads();
    bf16x8 af[2], bfr[2];
    #pragma unroll
    for (int mt = 0; mt < 2; mt++) af[mt] = *(const bf16x8*)&Al[wr * 32 + mt * 16 + l15][g * 8];
    #pragma unroll
    for (int nt = 0; nt < 2; nt++) bfr[nt] = *(const bf16x8*)&Bl[wc * 32 + nt * 16 + l15][g * 8];
    #pragma unroll
    for (int mt = 0; mt < 2; mt++)
      #pragma unroll
      for (int nt = 0; nt < 2; nt++)
        acc[mt][nt] = __builtin_amdgcn_mfma_f32_16x16x32_bf16(af[mt], bfr[nt], acc[mt][nt], 0, 0, 0);
  }
  #pragma unroll
  for (int mt = 0; mt < 2; mt++)
    #pragma unroll
    for (int nt = 0; nt < 2; nt++)
      #pragma unroll
      for (int r = 0; r < 4; r++) {
        int mm = m0 + wr * 32 + mt * 16 + (g << 2) + r;
        int nn = n0 + wc * 32 + nt * 16 + l15;
        if (mm < M) out[(size_t)mm * N + nn] = acc[mt][nt][r] + bias[nn];
      }
}

// ---------------- fused RMSNorm + RoPE + KV-window scatter ----------------
__launch_bounds__(256)
__global__ void k_norm_rope(const float* __restrict__ qp, const float* __restrict__ kp,
                            const float* __restrict__ vp, const float* __restrict__ gq,
                            const float* __restrict__ gk, const float* __restrict__ freqs,
                            const int* __restrict__ gs, const int* __restrict__ csp,
                            int S, int KVcap,
                            u16* __restrict__ rq, u16* __restrict__ K_all,
                            u16* __restrict__ VT) {
  const int t = blockIdx.x;
  const int tid = threadIdx.x;
  const float* q = qp + (size_t)t * MODEL_DIM;
  const float* k = kp + (size_t)t * MODEL_DIM;
  const float* v = vp + (size_t)t * MODEL_DIM;
  float sq = 0.f, sk = 0.f;
  for (int j = tid; j < MODEL_DIM; j += 256) {
    float a = q[j]; sq += a * a;
    float b = k[j]; sk += b * b;
  }
  #pragma unroll
  for (int off = 32; off > 0; off >>= 1) {
    sq += __shfl_down(sq, off, 64);
    sk += __shfl_down(sk, off, 64);
  }
  __shared__ float red[8];
  int wv_ = tid >> 6, l = tid & 63;
  if (l == 0) { red[wv_] = sq; red[4 + wv_] = sk; }
  __syncthreads();
  sq = red[0] + red[1] + red[2] + red[3];
  sk = red[4] + red[5] + red[6] + red[7];
  const float rq_s = rsqrtf(sq * (1.0f / MODEL_DIM) + 1e-6f);
  const float rk_s = rsqrtf(sk * (1.0f / MODEL_DIM) + 1e-6f);

  const int cs = csp[0];
  const int h = gs[1], ww = gs[2];
  const int hw = h * ww;
  const int sf = cs / hw;                 // start_frame
  const int fi = t / hw;
  const int rr = t - fi * hw;
  const int hi = rr / ww;
  const int wi = rr - hi * ww;
  const int ce = cs + S;
  int wst = ce - MAX_ATTN_W; if (wst < 0) wst = 0;
  const int jj = cs + t - wst;

  for (int p = tid; p < NHEADS * 64; p += 256) {
    int n = p >> 6, c = p & 63;
    int pos = (c < 22) ? (sf + fi) : ((c < 43) ? hi : wi);
    float cv = freqs[(pos * 64 + c) * 2];
    float sv = freqs[(pos * 64 + c) * 2 + 1];
    int j0 = n * HDIM + 2 * c;
    float qr = q[j0] * rq_s * gq[j0];
    float qi = q[j0 + 1] * rq_s * gq[j0 + 1];
    u32 oq = (u32)f2bf(qr * cv - qi * sv) | ((u32)f2bf(qr * sv + qi * cv) << 16);
    *(u32*)(rq + ((size_t)n * S + t) * HDIM + 2 * c) = oq;
    float kr = k[j0] * rk_s * gk[j0];
    float ki = k[j0 + 1] * rk_s * gk[j0 + 1];
    u32 ok = (u32)f2bf(kr * cv - ki * sv) | ((u32)f2bf(kr * sv + ki * cv) << 16);
    *(u32*)(K_all + ((size_t)n * KVcap + jj) * HDIM + 2 * c) = ok;
  }
  for (int j = tid; j < MODEL_DIM; j += 256) {
    int n = j >> 7, d = j & 127;
    VT[((size_t)n * HDIM + d) * KVcap + jj] = f2bf(v[j]);
  }
}

// ---------------- flash attention, bf16 MFMA ----------------
__launch_bounds__(256)
__global__ void k_attn(const u16* __restrict__ rq, const u16* __restrict__ K_all,
                       const u16* __restrict__ VT, u16* __restrict__ attn_out,
                       const int* __restrict__ csp, int S, int KVcap) {
  __shared__ __align__(16) u16 Klds[64][136];
  __shared__ __align__(16) u16 Vlds[128][72];
  __shared__ __align__(16) float Plds[64][68];

  const int tid = threadIdx.x;
  const int w = tid >> 6;
  const int l = tid & 63;
  const int l15 = l & 15;
  const int g = l >> 4;
  const int head = blockIdx.y;
  const int q0 = blockIdx.x * 64;

  const int cs = csp[0];
  const int ce = cs + S;
  int wst = ce - MAX_ATTN_W; if (wst < 0) wst = 0;
  const int KV = ce - wst;

  // Q fragments held in registers for the whole kernel (A-frag: row=l&15, k=(l>>4)*8+i)
  bf16x8 qf[4];
  {
    int qrow = q0 + (w << 4) + l15;
    if (qrow < S) {
      const u16* qp = rq + ((size_t)head * S + qrow) * HDIM + g * 8;
      #pragma unroll
      for (int ds = 0; ds < 4; ds++) qf[ds] = *(const bf16x8*)(qp + ds * 32);
    } else {
      bf16x8 z;
      #pragma unroll
      for (int i = 0; i < 8; i++) z[i] = (__bf16)0.0f;
      #pragma unroll
      for (int ds = 0; ds < 4; ds++) qf[ds] = z;
    }
  }

  f32x4 o[8];
  #pragma unroll
  for (int dt = 0; dt < 8; dt++) o[dt] = (f32x4){0.f, 0.f, 0.f, 0.f};
  float m[4], lsum[4];
  #pragma unroll
  for (int r = 0; r < 4; r++) { m[r] = -3.0e38f; lsum[r] = 0.f; }

  const u16* Kh = K_all + (size_t)head * KVcap * HDIM;
  const u16* Vh = VT + (size_t)head * HDIM * KVcap;
  const float rscale = 0.08838834764831845f;   // 1/sqrt(128)

  const int ntiles = (KV + 63) >> 6;
  for (int t = 0; t < ntiles; t++) {
    const int key0 = t << 6;
    __syncthreads();
    // stage K tile [key(64)][d(128)]
    #pragma unroll
    for (int i = 0; i < 4; i++) {
      int cid = tid + 256 * i;
      int krow = cid >> 4;
      int col = (cid & 15) * 8;
      int gk_ = key0 + krow;
      uint4 kv4 = make_uint4(0, 0, 0, 0);
      if (gk_ < KV) kv4 = *(const uint4*)(Kh + (size_t)gk_ * HDIM + col);
      *(uint4*)&Klds[krow][col] = kv4;
    }
    // stage V^T tile [d(128)][key(64)]
    #pragma unroll
    for (int i = 0; i < 4; i++) {
      int cid = tid + 256 * i;
      int d = cid >> 3;
      int kc = (cid & 7) * 8;
      const u16* src = Vh + (size_t)d * KVcap + key0 + kc;
      uint4 vv4;
      if (key0 + kc + 8 <= KV) {
        vv4 = *(const uint4*)src;
      } else {
        alignas(16) u16 tmp[8];
        #pragma unroll
        for (int j = 0; j < 8; j++) tmp[j] = (key0 + kc + j < KV) ? src[j] : (u16)0;
        vv4 = *(const uint4*)tmp;
      }
      *(uint4*)&Vlds[d][kc] = vv4;
    }
    __syncthreads();

    // QK^T : D[row=q][col=key]
    f32x4 s[4];
    #pragma unroll
    for (int kt = 0; kt < 4; kt++) {
      s[kt] = (f32x4){0.f, 0.f, 0.f, 0.f};
      #pragma unroll
      for (int ds = 0; ds < 4; ds++) {
        bf16x8 kf = *(const bf16x8*)&Klds[kt * 16 + l15][ds * 32 + g * 8];
        s[kt] = __builtin_amdgcn_mfma_f32_16x16x32_bf16(qf[ds], kf, s[kt], 0, 0, 0);
      }
    }

    // online softmax (rows = (l>>4)*4 + r within this wave's 16 q rows)
    float tmax[4] = {-3.0e38f, -3.0e38f, -3.0e38f, -3.0e38f};
    #pragma unroll
    for (int kt = 0; kt < 4; kt++) {
      int key = key0 + kt * 16 + l15;
      bool okk = key < KV;
      #pragma unroll
      for (int r = 0; r < 4; r++) {
        float v = s[kt][r] * rscale;
        v = okk ? v : -3.0e38f;
        s[kt][r] = v;
        tmax[r] = fmaxf(tmax[r], v);
      }
    }
    #pragma unroll
    for (int off = 1; off < 16; off <<= 1)
      #pragma unroll
      for (int r = 0; r < 4; r++)
        tmax[r] = fmaxf(tmax[r], __shfl_xor(tmax[r], off, 16));
    float alpha[4];
    #pragma unroll
    for (int r = 0; r < 4; r++) {
      float nm = fmaxf(m[r], tmax[r]);
      alpha[r] = __expf(m[r] - nm);
      m[r] = nm;
    }
    float rs[4] = {0.f, 0.f, 0.f, 0.f};
    #pragma unroll
    for (int kt = 0; kt < 4; kt++)
      #pragma unroll
      for (int r = 0; r < 4; r++) {
        float p = __expf(s[kt][r] - m[r]);
        rs[r] += p;
        Plds[(w << 4) + (g << 2) + r][kt * 16 + l15] = p;
      }
    #pragma unroll
    for (int off = 1; off < 16; off <<= 1)
      #pragma unroll
      for (int r = 0; r < 4; r++)
        rs[r] += __shfl_xor(rs[r], off, 16);
    #pragma unroll
    for (int r = 0; r < 4; r++) lsum[r] = lsum[r] * alpha[r] + rs[r];
    #pragma unroll
    for (int dt = 0; dt < 8; dt++)
      #pragma unroll
      for (int r = 0; r < 4; r++) o[dt][r] *= alpha[r];

    // P (D-layout) -> A-frag layout via wave-private LDS region
    bf16x8 pf[2];
    #pragma unroll
    for (int c = 0; c < 2; c++) {
      f32x4 pa = *(const f32x4*)&Plds[(w << 4) + l15][c * 32 + g * 8];
      f32x4 pb = *(const f32x4*)&Plds[(w << 4) + l15][c * 32 + g * 8 + 4];
      #pragma unroll
      for (int i = 0; i < 4; i++) { pf[c][i] = (__bf16)pa[i]; pf[c][i + 4] = (__bf16)pb[i]; }
    }
    // PV: O[q][d] += P[q][key] * V[key][d]   (B-frag from V^T tile)
    #pragma unroll
    for (int dt = 0; dt < 8; dt++) {
      #pragma unroll
      for (int c = 0; c < 2; c++) {
        bf16x8 vf = *(const bf16x8*)&Vlds[dt * 16 + l15][c * 32 + g * 8];
        o[dt] = __builtin_amdgcn_mfma_f32_16x16x32_bf16(pf[c], vf, o[dt], 0, 0, 0);
      }
    }
  }

  // epilogue: divide by softmax denom, store bf16 attn_out[token][n*128+d]
  #pragma unroll
  for (int r = 0; r < 4; r++) {
    int q = q0 + (w << 4) + (g << 2) + r;
    if (q < S) {
      float rl = 1.0f / lsum[r];
      #pragma unroll
      for (int dt = 0; dt < 8; dt++)
        attn_out[(size_t)q * MODEL_DIM + head * HDIM + dt * 16 + l15] = f2bf(o[dt][r] * rl);
    }
  }
}

extern "C" void kernel_launch(void* const* d_in, const int* in_sizes, int n_in,
                              void* d_out, int out_size, void* d_ws, size_t ws_size,
                              hipStream_t stream) {
  (void)n_in; (void)out_size; (void)ws_size;
  const float* x  = (const float*)d_in[0];
  const float* wq = (const float*)d_in[1];
  const float* bq = (const float*)d_in[2];
  const float* wk = (const float*)d_in[3];
  const float* bk = (const float*)d_in[4];
  const float* wv = (const float*)d_in[5];
  const float* bv = (const float*)d_in[6];
  const float* wo = (const float*)d_in[7];
  const float* bo = (const float*)d_in[8];
  const float* gq = (const float*)d_in[9];
  const float* gk = (const float*)d_in[10];
  const float* freqs = (const float*)d_in[11];
  const float* k_cache = (const float*)d_in[12];
  const float* v_cache = (const float*)d_in[13];
  const int* gs  = (const int*)d_in[14];
  const int* csp = (const int*)d_in[15];

  const int S = in_sizes[0] / MODEL_DIM;
  const int CACHE = in_sizes[12] / (NHEADS * HDIM);
  const int KVcap = (CACHE < MAX_ATTN_W) ? CACHE : MAX_ATTN_W;

  char* ws = (char*)d_ws;
  size_t off = 0;
  auto alloc = [&](size_t bytes) {
    char* p = ws + off;
    off += (bytes + 255) & ~(size_t)255;
    return p;
  };
  u16* xb   = (u16*)alloc((size_t)S * MODEL_DIM * 2);
  u16* wqb  = (u16*)alloc((size_t)MODEL_DIM * MODEL_DIM * 2);
  u16* wkb  = (u16*)alloc((size_t)MODEL_DIM * MODEL_DIM * 2);
  u16* wvb  = (u16*)alloc((size_t)MODEL_DIM * MODEL_DIM * 2);
  u16* wob  = (u16*)alloc((size_t)MODEL_DIM * MODEL_DIM * 2);
  float* q_pre = (float*)alloc((size_t)S * MODEL_DIM * 4);
  float* k_pre = (float*)alloc((size_t)S * MODEL_DIM * 4);
  float* v_pre = (float*)alloc((size_t)S * MODEL_DIM * 4);
  u16* rqb   = (u16*)alloc((size_t)NHEADS * S * HDIM * 2);
  u16* K_all = (u16*)alloc((size_t)NHEADS * KVcap * HDIM * 2);
  u16* VT    = (u16*)alloc((size_t)NHEADS * HDIM * KVcap * 2);
  u16* attn_o = (u16*)alloc((size_t)S * MODEL_DIM * 2);

  const int nx4 = S * MODEL_DIM / 4;
  const int nw4 = MODEL_DIM * MODEL_DIM / 4;
  hipLaunchKernelGGL(k_conv_bf16, dim3((nx4 + 255) / 256), dim3(256), 0, stream, x, xb, nx4);
  hipLaunchKernelGGL(k_conv_bf16, dim3((nw4 + 255) / 256), dim3(256), 0, stream, wq, wqb, nw4);
  hipLaunchKernelGGL(k_conv_bf16, dim3((nw4 + 255) / 256), dim3(256), 0, stream, wk, wkb, nw4);
  hipLaunchKernelGGL(k_conv_bf16, dim3((nw4 + 255) / 256), dim3(256), 0, stream, wv, wvb, nw4);
  hipLaunchKernelGGL(k_conv_bf16, dim3((nw4 + 255) / 256), dim3(256), 0, stream, wo, wob, nw4);

  hipLaunchKernelGGL(k_build_kold, dim3(2048), dim3(256), 0, stream, k_cache, K_all, csp, S, KVcap);
  hipLaunchKernelGGL(k_build_vtold, dim3(2048), dim3(256), 0, stream, v_cache, VT, csp, S, KVcap);

  dim3 ggrid((S + 63) / 64, MODEL_DIM / 64);
  hipLaunchKernelGGL(k_gemm_bt, ggrid, dim3(256), 0, stream, xb, wqb, bq, q_pre, S, MODEL_DIM, MODEL_DIM);
  hipLaunchKernelGGL(k_gemm_bt, ggrid, dim3(256), 0, stream, xb, wkb, bk, k_pre, S, MODEL_DIM, MODEL_DIM);
  hipLaunchKernelGGL(k_gemm_bt, ggrid, dim3(256), 0, stream, xb, wvb, bv, v_pre, S, MODEL_DIM, MODEL_DIM);

  hipLaunchKernelGGL(k_norm_rope, dim3(S), dim3(256), 0, stream,
                     q_pre, k_pre, v_pre, gq, gk, freqs, gs, csp, S, KVcap, rqb, K_all, VT);

  hipLaunchKernelGGL(k_attn, dim3((S + 63) / 64, NHEADS), dim3(256), 0, stream,
                     rqb, K_all, VT, attn_o, csp, S, KVcap);

  hipLaunchKernelGGL(k_gemm_bt, ggrid, dim3(256), 0, stream,
                     attn_o, wob, bo, (float*)d_out, S, MODEL_DIM, MODEL_DIM);
}

// Round 2
// 517.983 us; speedup vs baseline: 1.9738x; 1.9738x over previous
//
#include <hip/hip_runtime.h>

#define NHEADS 12
#define HDIM 128
#define MODEL_DIM 1536
#define MAX_ATTN_W 13200
#define NSPLIT 12

typedef unsigned short u16;
typedef unsigned int u32;
typedef float f32x4 __attribute__((ext_vector_type(4)));
typedef __bf16 bf16x8 __attribute__((ext_vector_type(8)));

static __device__ __forceinline__ u16 f2bf(float f) {
  union { __bf16 h; u16 u; } cv;
  cv.h = (__bf16)f;
  return cv.u;
}
static __device__ __forceinline__ float bf2f(u16 u) {
  union { u32 u; float f; } cv;
  cv.u = ((u32)u) << 16;
  return cv.f;
}

// ---------------- fp32 -> bf16 convert ----------------
__global__ void k_conv_bf16(const float* __restrict__ src, u16* __restrict__ dst, int n4) {
  int i = blockIdx.x * blockDim.x + threadIdx.x;
  if (i >= n4) return;
  float4 v = ((const float4*)src)[i];
  u32 lo = (u32)f2bf(v.x) | ((u32)f2bf(v.y) << 16);
  u32 hi = (u32)f2bf(v.z) | ((u32)f2bf(v.w) << 16);
  ((uint2*)dst)[i] = make_uint2(lo, hi);
}

// ---------------- old cache -> bf16 K window [n][jj][d] ----------------
__global__ void k_build_kold(const float* __restrict__ kc, u16* __restrict__ K_all,
                             const int* __restrict__ csp, int S, int KVcap) {
  const int cs = csp[0];
  const int ce = cs + S;
  int wst = ce - MAX_ATTN_W; if (wst < 0) wst = 0;
  const int oldlen = cs - wst;
  const long per = (long)oldlen * 16;   // 16 chunks of 8 along d
  const long total = per * NHEADS;
  for (long c = blockIdx.x * (long)blockDim.x + threadIdx.x; c < total;
       c += (long)gridDim.x * blockDim.x) {
    int n = (int)(c / per);
    long r = c - (long)n * per;
    int jo = (int)(r >> 4);
    int dc = ((int)r & 15) * 8;
    const float* s = kc + ((size_t)(wst + jo) * NHEADS + n) * HDIM + dc;
    float4 a = *(const float4*)s;
    float4 b = *(const float4*)(s + 4);
    uint4 o;
    o.x = (u32)f2bf(a.x) | ((u32)f2bf(a.y) << 16);
    o.y = (u32)f2bf(a.z) | ((u32)f2bf(a.w) << 16);
    o.z = (u32)f2bf(b.x) | ((u32)f2bf(b.y) << 16);
    o.w = (u32)f2bf(b.z) | ((u32)f2bf(b.w) << 16);
    *(uint4*)(K_all + ((size_t)n * KVcap + jo) * HDIM + dc) = o;
  }
}

// ---------------- old cache -> bf16 V^T window [n][d][jj] ----------------
__global__ void k_build_vtold(const float* __restrict__ vc, u16* __restrict__ VT,
                              const int* __restrict__ csp, int S, int KVcap) {
  const int cs = csp[0];
  const int ce = cs + S;
  int wst = ce - MAX_ATTN_W; if (wst < 0) wst = 0;
  const int oldlen = cs - wst;
  const int nj8 = (oldlen + 7) >> 3;
  const long per = (long)HDIM * nj8;
  const long total = per * NHEADS;
  for (long c = blockIdx.x * (long)blockDim.x + threadIdx.x; c < total;
       c += (long)gridDim.x * blockDim.x) {
    int n = (int)(c / per);
    long r = c - (long)n * per;
    int d = (int)(r / nj8);
    int jc = (int)(r - (long)d * nj8);
    int jbase = jc * 8;
    int cnt = oldlen - jbase; if (cnt > 8) cnt = 8;
    u16* dst = VT + ((size_t)n * HDIM + d) * KVcap + jbase;
    if (cnt == 8) {
      u32 words[4];
      #pragma unroll
      for (int i2 = 0; i2 < 4; i2++) {
        float e0 = vc[((size_t)(wst + jbase + 2 * i2) * NHEADS + n) * HDIM + d];
        float e1 = vc[((size_t)(wst + jbase + 2 * i2 + 1) * NHEADS + n) * HDIM + d];
        words[i2] = (u32)f2bf(e0) | ((u32)f2bf(e1) << 16);
      }
      *(uint4*)dst = make_uint4(words[0], words[1], words[2], words[3]);
    } else {
      for (int i = 0; i < cnt; i++)
        dst[i] = f2bf(vc[((size_t)(wst + jbase + i) * NHEADS + n) * HDIM + d]);
    }
  }
}

// ---------------- bf16 GEMM: out[m][n] = sum_k A[m][k]*B[n][k] + bias[n] ----------------
__launch_bounds__(256)
__global__ void k_gemm_bt(const u16* __restrict__ A, const u16* __restrict__ B,
                          const float* __restrict__ bias, float* __restrict__ out,
                          int M, int N, int K) {
  __shared__ __align__(16) u16 Al[64][40];
  __shared__ __align__(16) u16 Bl[64][40];
  const int tid = threadIdx.x;
  const int w = tid >> 6, l = tid & 63, l15 = l & 15, g = l >> 4;
  const int wr = w >> 1, wc = w & 1;
  const int m0 = blockIdx.x * 64, n0 = blockIdx.y * 64;
  f32x4 acc[2][2] = {};
  const int row = tid >> 2, colc = (tid & 3) * 8;
  for (int k0 = 0; k0 < K; k0 += 32) {
    __syncthreads();
    uint4 av = make_uint4(0, 0, 0, 0);
    int gm = m0 + row;
    if (gm < M) av = *(const uint4*)(A + (size_t)gm * K + k0 + colc);
    *(uint4*)&Al[row][colc] = av;
    uint4 bv = *(const uint4*)(B + (size_t)(n0 + row) * K + k0 + colc);
    *(uint4*)&Bl[row][colc] = bv;
    __syncthreads();
    bf16x8 af[2], bfr[2];
    #pragma unroll
    for (int mt = 0; mt < 2; mt++) af[mt] = *(const bf16x8*)&Al[wr * 32 + mt * 16 + l15][g * 8];
    #pragma unroll
    for (int nt = 0; nt < 2; nt++) bfr[nt] = *(const bf16x8*)&Bl[wc * 32 + nt * 16 + l15][g * 8];
    #pragma unroll
    for (int mt = 0; mt < 2; mt++)
      #pragma unroll
      for (int nt = 0; nt < 2; nt++)
        acc[mt][nt] = __builtin_amdgcn_mfma_f32_16x16x32_bf16(af[mt], bfr[nt], acc[mt][nt], 0, 0, 0);
  }
  #pragma unroll
  for (int mt = 0; mt < 2; mt++)
    #pragma unroll
    for (int nt = 0; nt < 2; nt++)
      #pragma unroll
      for (int r = 0; r < 4; r++) {
        int mm = m0 + wr * 32 + mt * 16 + (g << 2) + r;
        int nn = n0 + wc * 32 + nt * 16 + l15;
        if (mm < M) out[(size_t)mm * N + nn] = acc[mt][nt][r] + bias[nn];
      }
}

// ---------------- fused QKV GEMM (3 weight matrices, one launch) ----------------
__launch_bounds__(256)
__global__ void k_gemm_qkv(const u16* __restrict__ A,
                           const u16* __restrict__ B0, const u16* __restrict__ B1,
                           const u16* __restrict__ B2,
                           const float* __restrict__ bias0, const float* __restrict__ bias1,
                           const float* __restrict__ bias2,
                           float* __restrict__ o0, float* __restrict__ o1, float* __restrict__ o2,
                           int M, int N, int K) {
  __shared__ __align__(16) u16 Al[64][40];
  __shared__ __align__(16) u16 Bl[64][40];
  const int nblk = N / 64;
  const int which = blockIdx.y / nblk;
  const int n0 = (blockIdx.y % nblk) * 64;
  const u16* B = (which == 0) ? B0 : ((which == 1) ? B1 : B2);
  const float* bias = (which == 0) ? bias0 : ((which == 1) ? bias1 : bias2);
  float* out = (which == 0) ? o0 : ((which == 1) ? o1 : o2);
  const int tid = threadIdx.x;
  const int w = tid >> 6, l = tid & 63, l15 = l & 15, g = l >> 4;
  const int wr = w >> 1, wc = w & 1;
  const int m0 = blockIdx.x * 64;
  f32x4 acc[2][2] = {};
  const int row = tid >> 2, colc = (tid & 3) * 8;
  for (int k0 = 0; k0 < K; k0 += 32) {
    __syncthreads();
    uint4 av = make_uint4(0, 0, 0, 0);
    int gm = m0 + row;
    if (gm < M) av = *(const uint4*)(A + (size_t)gm * K + k0 + colc);
    *(uint4*)&Al[row][colc] = av;
    uint4 bv = *(const uint4*)(B + (size_t)(n0 + row) * K + k0 + colc);
    *(uint4*)&Bl[row][colc] = bv;
    __syncthreads();
    bf16x8 af[2], bfr[2];
    #pragma unroll
    for (int mt = 0; mt < 2; mt++) af[mt] = *(const bf16x8*)&Al[wr * 32 + mt * 16 + l15][g * 8];
    #pragma unroll
    for (int nt = 0; nt < 2; nt++) bfr[nt] = *(const bf16x8*)&Bl[wc * 32 + nt * 16 + l15][g * 8];
    #pragma unroll
    for (int mt = 0; mt < 2; mt++)
      #pragma unroll
      for (int nt = 0; nt < 2; nt++)
        acc[mt][nt] = __builtin_amdgcn_mfma_f32_16x16x32_bf16(af[mt], bfr[nt], acc[mt][nt], 0, 0, 0);
  }
  #pragma unroll
  for (int mt = 0; mt < 2; mt++)
    #pragma unroll
    for (int nt = 0; nt < 2; nt++)
      #pragma unroll
      for (int r = 0; r < 4; r++) {
        int mm = m0 + wr * 32 + mt * 16 + (g << 2) + r;
        int nn = n0 + wc * 32 + nt * 16 + l15;
        if (mm < M) out[(size_t)mm * N + nn] = acc[mt][nt][r] + bias[nn];
      }
}

// ---------------- fused RMSNorm + RoPE + KV-window scatter ----------------
__launch_bounds__(256)
__global__ void k_norm_rope(const float* __restrict__ qp, const float* __restrict__ kp,
                            const float* __restrict__ vp, const float* __restrict__ gq,
                            const float* __restrict__ gk, const float* __restrict__ freqs,
                            const int* __restrict__ gs, const int* __restrict__ csp,
                            int S, int KVcap,
                            u16* __restrict__ rq, u16* __restrict__ K_all,
                            u16* __restrict__ VT) {
  const int t = blockIdx.x;
  const int tid = threadIdx.x;
  const float* q = qp + (size_t)t * MODEL_DIM;
  const float* k = kp + (size_t)t * MODEL_DIM;
  const float* v = vp + (size_t)t * MODEL_DIM;
  float sq = 0.f, sk = 0.f;
  for (int j = tid; j < MODEL_DIM; j += 256) {
    float a = q[j]; sq += a * a;
    float b = k[j]; sk += b * b;
  }
  #pragma unroll
  for (int off = 32; off > 0; off >>= 1) {
    sq += __shfl_down(sq, off, 64);
    sk += __shfl_down(sk, off, 64);
  }
  __shared__ float red[8];
  int wv_ = tid >> 6, l = tid & 63;
  if (l == 0) { red[wv_] = sq; red[4 + wv_] = sk; }
  __syncthreads();
  sq = red[0] + red[1] + red[2] + red[3];
  sk = red[4] + red[5] + red[6] + red[7];
  const float rq_s = rsqrtf(sq * (1.0f / MODEL_DIM) + 1e-6f);
  const float rk_s = rsqrtf(sk * (1.0f / MODEL_DIM) + 1e-6f);

  const int cs = csp[0];
  const int h = gs[1], ww = gs[2];
  const int hw = h * ww;
  const int sf = cs / hw;                 // start_frame
  const int fi = t / hw;
  const int rr = t - fi * hw;
  const int hi = rr / ww;
  const int wi = rr - hi * ww;
  const int ce = cs + S;
  int wst = ce - MAX_ATTN_W; if (wst < 0) wst = 0;
  const int jj = cs + t - wst;

  for (int p = tid; p < NHEADS * 64; p += 256) {
    int n = p >> 6, c = p & 63;
    int pos = (c < 22) ? (sf + fi) : ((c < 43) ? hi : wi);
    float cv = freqs[(pos * 64 + c) * 2];
    float sv = freqs[(pos * 64 + c) * 2 + 1];
    int j0 = n * HDIM + 2 * c;
    float qr = q[j0] * rq_s * gq[j0];
    float qi = q[j0 + 1] * rq_s * gq[j0 + 1];
    u32 oq = (u32)f2bf(qr * cv - qi * sv) | ((u32)f2bf(qr * sv + qi * cv) << 16);
    *(u32*)(rq + ((size_t)n * S + t) * HDIM + 2 * c) = oq;
    float kr = k[j0] * rk_s * gk[j0];
    float ki = k[j0 + 1] * rk_s * gk[j0 + 1];
    u32 ok = (u32)f2bf(kr * cv - ki * sv) | ((u32)f2bf(kr * sv + ki * cv) << 16);
    *(u32*)(K_all + ((size_t)n * KVcap + jj) * HDIM + 2 * c) = ok;
  }
  for (int j = tid; j < MODEL_DIM; j += 256) {
    int n = j >> 7, d = j & 127;
    VT[((size_t)n * HDIM + d) * KVcap + jj] = f2bf(v[j]);
  }
}

// ---------------- flash attention, split-K over the KV window ----------------
// Partials per (head, split): po = normalized per-split output (bf16), pm = running max,
// pl = softmax denom. Combined by k_attn_reduce.
__launch_bounds__(256, 4)
__global__ void k_attn_split(const u16* __restrict__ rq, const u16* __restrict__ K_all,
                             const u16* __restrict__ VT,
                             u16* __restrict__ po, float* __restrict__ pm, float* __restrict__ pl,
                             const int* __restrict__ csp, int S, int KVcap) {
  __shared__ __align__(16) u16 Klds[64][132];
  __shared__ __align__(16) u16 Vlds[128][68];
  // P (bf16, [64][68]) overlays Klds: written only after a barrier that ends all K reads.
  u16 (*Plds)[68] = reinterpret_cast<u16(*)[68]>(&Klds[0][0]);

  const int tid = threadIdx.x;
  const int w = tid >> 6;
  const int l = tid & 63;
  const int l15 = l & 15;
  const int g = l >> 4;
  const int head = blockIdx.y;
  const int split = blockIdx.z;
  const int q0 = blockIdx.x * 64;

  const int cs = csp[0];
  const int ce = cs + S;
  int wst = ce - MAX_ATTN_W; if (wst < 0) wst = 0;
  const int KV = ce - wst;
  const int chunk = (((KV + NSPLIT - 1) / NSPLIT) + 63) & ~63;
  const int kstart = split * chunk;
  int kend = kstart + chunk; if (kend > KV) kend = KV;

  const size_t pbase = ((size_t)head * NSPLIT + split) * S;

  if (kstart >= kend) {
    // empty split: record -inf / 0 so the reduce ignores it
    #pragma unroll
    for (int r = 0; r < 4; r++) {
      int q = q0 + (w << 4) + (g << 2) + r;
      if (q < S && l15 == 0) { pm[pbase + q] = -3.0e38f; pl[pbase + q] = 0.f; }
    }
    return;
  }

  // Q fragments held in registers (A-frag: row=l&15, k=(l>>4)*8+i)
  bf16x8 qf[4];
  {
    int qrow = q0 + (w << 4) + l15;
    if (qrow < S) {
      const u16* qp = rq + ((size_t)head * S + qrow) * HDIM + g * 8;
      #pragma unroll
      for (int ds = 0; ds < 4; ds++) qf[ds] = *(const bf16x8*)(qp + ds * 32);
    } else {
      bf16x8 z;
      #pragma unroll
      for (int i = 0; i < 8; i++) z[i] = (__bf16)0.0f;
      #pragma unroll
      for (int ds = 0; ds < 4; ds++) qf[ds] = z;
    }
  }

  f32x4 o[8];
  #pragma unroll
  for (int dt = 0; dt < 8; dt++) o[dt] = (f32x4){0.f, 0.f, 0.f, 0.f};
  float m[4], lsum[4];
  #pragma unroll
  for (int r = 0; r < 4; r++) { m[r] = -3.0e38f; lsum[r] = 0.f; }

  const u16* Kh = K_all + (size_t)head * KVcap * HDIM;
  const u16* Vh = VT + (size_t)head * HDIM * KVcap;
  const float rscale = 0.08838834764831845f;   // 1/sqrt(128)

  const int ntiles = (kend - kstart + 63) >> 6;
  for (int t = 0; t < ntiles; t++) {
    const int key0 = kstart + (t << 6);
    __syncthreads();   // prev tile's P reads (Klds overlay) + V reads done
    // stage K tile [key(64)][d(128)]
    #pragma unroll
    for (int i = 0; i < 4; i++) {
      int cid = tid + 256 * i;
      int krow = cid >> 4;
      int col = (cid & 15) * 8;
      int gk_ = key0 + krow;
      uint4 kv4 = make_uint4(0, 0, 0, 0);
      if (gk_ < kend) kv4 = *(const uint4*)(Kh + (size_t)gk_ * HDIM + col);
      *(uint4*)&Klds[krow][col] = kv4;
    }
    // stage V^T tile [d(128)][key(64)]
    #pragma unroll
    for (int i = 0; i < 4; i++) {
      int cid = tid + 256 * i;
      int d = cid >> 3;
      int kc = (cid & 7) * 8;
      const u16* src = Vh + (size_t)d * KVcap + key0 + kc;
      uint4 vv4;
      if (key0 + kc + 8 <= kend) {
        vv4 = *(const uint4*)src;
      } else {
        alignas(16) u16 tmp[8];
        #pragma unroll
        for (int j = 0; j < 8; j++) tmp[j] = (key0 + kc + j < kend) ? src[j] : (u16)0;
        vv4 = *(const uint4*)tmp;
      }
      *(uint4*)&Vlds[d][kc] = vv4;
    }
    __syncthreads();

    // QK^T : D[row=q][col=key]
    f32x4 s[4];
    #pragma unroll
    for (int kt = 0; kt < 4; kt++) {
      s[kt] = (f32x4){0.f, 0.f, 0.f, 0.f};
      #pragma unroll
      for (int ds = 0; ds < 4; ds++) {
        bf16x8 kf = *(const bf16x8*)&Klds[kt * 16 + l15][ds * 32 + g * 8];
        s[kt] = __builtin_amdgcn_mfma_f32_16x16x32_bf16(qf[ds], kf, s[kt], 0, 0, 0);
      }
    }

    // online softmax in registers
    float tmax[4] = {-3.0e38f, -3.0e38f, -3.0e38f, -3.0e38f};
    #pragma unroll
    for (int kt = 0; kt < 4; kt++) {
      int key = key0 + kt * 16 + l15;
      bool okk = key < kend;
      #pragma unroll
      for (int r = 0; r < 4; r++) {
        float v = s[kt][r] * rscale;
        v = okk ? v : -3.0e38f;
        s[kt][r] = v;
        tmax[r] = fmaxf(tmax[r], v);
      }
    }
    #pragma unroll
    for (int off = 1; off < 16; off <<= 1)
      #pragma unroll
      for (int r = 0; r < 4; r++)
        tmax[r] = fmaxf(tmax[r], __shfl_xor(tmax[r], off, 16));
    float alpha[4];
    #pragma unroll
    for (int r = 0; r < 4; r++) {
      float nm = fmaxf(m[r], tmax[r]);
      alpha[r] = __expf(m[r] - nm);
      m[r] = nm;
    }
    float rs[4] = {0.f, 0.f, 0.f, 0.f};
    u16 pu[4][4];
    #pragma unroll
    for (int kt = 0; kt < 4; kt++)
      #pragma unroll
      for (int r = 0; r < 4; r++) {
        float p = __expf(s[kt][r] - m[r]);
        rs[r] += p;
        pu[kt][r] = f2bf(p);
      }
    #pragma unroll
    for (int off = 1; off < 16; off <<= 1)
      #pragma unroll
      for (int r = 0; r < 4; r++)
        rs[r] += __shfl_xor(rs[r], off, 16);
    #pragma unroll
    for (int r = 0; r < 4; r++) lsum[r] = lsum[r] * alpha[r] + rs[r];
    #pragma unroll
    for (int dt = 0; dt < 8; dt++)
      #pragma unroll
      for (int r = 0; r < 4; r++) o[dt][r] *= alpha[r];

    __syncthreads();   // all waves done reading Klds -> safe to overwrite as P
    #pragma unroll
    for (int kt = 0; kt < 4; kt++)
      #pragma unroll
      for (int r = 0; r < 4; r++)
        Plds[(w << 4) + (g << 2) + r][kt * 16 + l15] = pu[kt][r];

    // P A-frag read (own wave's rows; DS ops are in-order per wave)
    bf16x8 pf[2];
    #pragma unroll
    for (int c = 0; c < 2; c++)
      pf[c] = *(const bf16x8*)&Plds[(w << 4) + l15][c * 32 + g * 8];

    // PV: O[q][d] += P[q][key] * V[key][d]   (B-frag from V^T tile)
    #pragma unroll
    for (int dt = 0; dt < 8; dt++) {
      #pragma unroll
      for (int c = 0; c < 2; c++) {
        bf16x8 vf = *(const bf16x8*)&Vlds[dt * 16 + l15][c * 32 + g * 8];
        o[dt] = __builtin_amdgcn_mfma_f32_16x16x32_bf16(pf[c], vf, o[dt], 0, 0, 0);
      }
    }
  }

  // epilogue: per-split normalized partial (bf16) + m/l scalars
  #pragma unroll
  for (int r = 0; r < 4; r++) {
    int q = q0 + (w << 4) + (g << 2) + r;
    if (q < S) {
      float rl = (lsum[r] > 0.f) ? (1.0f / lsum[r]) : 0.f;
      #pragma unroll
      for (int dt = 0; dt < 8; dt++)
        po[(pbase + q) * HDIM + dt * 16 + l15] = f2bf(o[dt][r] * rl);
      if (l15 == 0) { pm[pbase + q] = m[r]; pl[pbase + q] = lsum[r]; }
    }
  }
}

// ---------------- combine split-K partials ----------------
__global__ void k_attn_reduce(const u16* __restrict__ po, const float* __restrict__ pm,
                              const float* __restrict__ pl, u16* __restrict__ attn_out,
                              int S) {
  const int t = blockIdx.x;
  const int h = blockIdx.y;
  const int d = threadIdx.x;   // 128 threads
  float ms[NSPLIT];
  float M = -3.0e38f;
  #pragma unroll
  for (int s = 0; s < NSPLIT; s++) {
    ms[s] = pm[((size_t)h * NSPLIT + s) * S + t];
    M = fmaxf(M, ms[s]);
  }
  float L = 0.f, acc = 0.f;
  #pragma unroll
  for (int s = 0; s < NSPLIT; s++) {
    float wgt = __expf(ms[s] - M) * pl[((size_t)h * NSPLIT + s) * S + t];
    L += wgt;
    acc += wgt * bf2f(po[(((size_t)h * NSPLIT + s) * S + t) * HDIM + d]);
  }
  attn_out[(size_t)t * MODEL_DIM + h * HDIM + d] = f2bf(acc / L);
}

extern "C" void kernel_launch(void* const* d_in, const int* in_sizes, int n_in,
                              void* d_out, int out_size, void* d_ws, size_t ws_size,
                              hipStream_t stream) {
  (void)n_in; (void)out_size; (void)ws_size;
  const float* x  = (const float*)d_in[0];
  const float* wq = (const float*)d_in[1];
  const float* bq = (const float*)d_in[2];
  const float* wk = (const float*)d_in[3];
  const float* bk = (const float*)d_in[4];
  const float* wv = (const float*)d_in[5];
  const float* bv = (const float*)d_in[6];
  const float* wo = (const float*)d_in[7];
  const float* bo = (const float*)d_in[8];
  const float* gq = (const float*)d_in[9];
  const float* gk = (const float*)d_in[10];
  const float* freqs = (const float*)d_in[11];
  const float* k_cache = (const float*)d_in[12];
  const float* v_cache = (const float*)d_in[13];
  const int* gs  = (const int*)d_in[14];
  const int* csp = (const int*)d_in[15];

  const int S = in_sizes[0] / MODEL_DIM;
  const int CACHE = in_sizes[12] / (NHEADS * HDIM);
  const int KVcap = (CACHE < MAX_ATTN_W) ? CACHE : MAX_ATTN_W;

  char* ws = (char*)d_ws;
  size_t off = 0;
  auto alloc = [&](size_t bytes) {
    char* p = ws + off;
    off += (bytes + 255) & ~(size_t)255;
    return p;
  };
  u16* xb   = (u16*)alloc((size_t)S * MODEL_DIM * 2);
  u16* wqb  = (u16*)alloc((size_t)MODEL_DIM * MODEL_DIM * 2);
  u16* wkb  = (u16*)alloc((size_t)MODEL_DIM * MODEL_DIM * 2);
  u16* wvb  = (u16*)alloc((size_t)MODEL_DIM * MODEL_DIM * 2);
  u16* wob  = (u16*)alloc((size_t)MODEL_DIM * MODEL_DIM * 2);
  float* q_pre = (float*)alloc((size_t)S * MODEL_DIM * 4);
  float* k_pre = (float*)alloc((size_t)S * MODEL_DIM * 4);
  float* v_pre = (float*)alloc((size_t)S * MODEL_DIM * 4);
  u16* rqb   = (u16*)alloc((size_t)NHEADS * S * HDIM * 2);
  u16* K_all = (u16*)alloc((size_t)NHEADS * KVcap * HDIM * 2);
  u16* VT    = (u16*)alloc((size_t)NHEADS * HDIM * KVcap * 2);
  u16* attn_o = (u16*)alloc((size_t)S * MODEL_DIM * 2);
  u16* po    = (u16*)alloc((size_t)NHEADS * NSPLIT * S * HDIM * 2);
  float* pm  = (float*)alloc((size_t)NHEADS * NSPLIT * S * 4);
  float* pl  = (float*)alloc((size_t)NHEADS * NSPLIT * S * 4);

  const int nx4 = S * MODEL_DIM / 4;
  const int nw4 = MODEL_DIM * MODEL_DIM / 4;
  hipLaunchKernelGGL(k_conv_bf16, dim3((nx4 + 255) / 256), dim3(256), 0, stream, x, xb, nx4);
  hipLaunchKernelGGL(k_conv_bf16, dim3((nw4 + 255) / 256), dim3(256), 0, stream, wq, wqb, nw4);
  hipLaunchKernelGGL(k_conv_bf16, dim3((nw4 + 255) / 256), dim3(256), 0, stream, wk, wkb, nw4);
  hipLaunchKernelGGL(k_conv_bf16, dim3((nw4 + 255) / 256), dim3(256), 0, stream, wv, wvb, nw4);
  hipLaunchKernelGGL(k_conv_bf16, dim3((nw4 + 255) / 256), dim3(256), 0, stream, wo, wob, nw4);

  hipLaunchKernelGGL(k_build_kold, dim3(2048), dim3(256), 0, stream, k_cache, K_all, csp, S, KVcap);
  hipLaunchKernelGGL(k_build_vtold, dim3(2048), dim3(256), 0, stream, v_cache, VT, csp, S, KVcap);

  hipLaunchKernelGGL(k_gemm_qkv, dim3((S + 63) / 64, 3 * MODEL_DIM / 64), dim3(256), 0, stream,
                     xb, wqb, wkb, wvb, bq, bk, bv, q_pre, k_pre, v_pre, S, MODEL_DIM, MODEL_DIM);

  hipLaunchKernelGGL(k_norm_rope, dim3(S), dim3(256), 0, stream,
                     q_pre, k_pre, v_pre, gq, gk, freqs, gs, csp, S, KVcap, rqb, K_all, VT);

  hipLaunchKernelGGL(k_attn_split, dim3((S + 63) / 64, NHEADS, NSPLIT), dim3(256), 0, stream,
                     rqb, K_all, VT, po, pm, pl, csp, S, KVcap);

  hipLaunchKernelGGL(k_attn_reduce, dim3(S, NHEADS), dim3(128), 0, stream, po, pm, pl, attn_o, S);

  hipLaunchKernelGGL(k_gemm_bt, dim3((S + 63) / 64, MODEL_DIM / 64), dim3(256), 0, stream,
                     attn_o, wob, bo, (float*)d_out, S, MODEL_DIM, MODEL_DIM);
}

// Round 3
// 378.281 us; speedup vs baseline: 2.7027x; 1.3693x over previous
//
#include <hip/hip_runtime.h>

#define NHEADS 12
#define HDIM 128
#define MODEL_DIM 1536
#define MAX_ATTN_W 13200
#define NSPLIT 12

typedef unsigned short u16;
typedef unsigned int u32;
typedef float f32x4 __attribute__((ext_vector_type(4)));
typedef __bf16 bf16x8 __attribute__((ext_vector_type(8)));

static __device__ __forceinline__ u16 f2bf(float f) {
  union { __bf16 h; u16 u; } cv;
  cv.h = (__bf16)f;
  return cv.u;
}
static __device__ __forceinline__ float bf2f(u16 u) {
  union { u32 u; float f; } cv;
  cv.u = ((u32)u) << 16;
  return cv.f;
}

// ---------------- fp32 -> bf16 convert (single buffer) ----------------
__global__ void k_conv_bf16(const float* __restrict__ src, u16* __restrict__ dst, int n4) {
  int i = blockIdx.x * blockDim.x + threadIdx.x;
  if (i >= n4) return;
  float4 v = ((const float4*)src)[i];
  u32 lo = (u32)f2bf(v.x) | ((u32)f2bf(v.y) << 16);
  u32 hi = (u32)f2bf(v.z) | ((u32)f2bf(v.w) << 16);
  ((uint2*)dst)[i] = make_uint2(lo, hi);
}

// ---------------- fp32 -> bf16 convert, 4 weight matrices in one launch ----------------
__global__ void k_conv_bf16_w4(const float* __restrict__ s0, const float* __restrict__ s1,
                               const float* __restrict__ s2, const float* __restrict__ s3,
                               u16* __restrict__ d0, u16* __restrict__ d1,
                               u16* __restrict__ d2, u16* __restrict__ d3, int n4) {
  int i = blockIdx.x * blockDim.x + threadIdx.x;
  if (i >= n4) return;
  const int which = blockIdx.y;
  const float* src = (which == 0) ? s0 : (which == 1) ? s1 : (which == 2) ? s2 : s3;
  u16* dst = (which == 0) ? d0 : (which == 1) ? d1 : (which == 2) ? d2 : d3;
  float4 v = ((const float4*)src)[i];
  u32 lo = (u32)f2bf(v.x) | ((u32)f2bf(v.y) << 16);
  u32 hi = (u32)f2bf(v.z) | ((u32)f2bf(v.w) << 16);
  ((uint2*)dst)[i] = make_uint2(lo, hi);
}

// ---------------- old cache -> bf16 K window [n][jj][d] (coalesced both sides) ----------------
__global__ void k_build_kold(const float* __restrict__ kc, u16* __restrict__ K_all,
                             const int* __restrict__ csp, int S, int KVcap) {
  const int cs = csp[0];
  const int ce = cs + S;
  int wst = ce - MAX_ATTN_W; if (wst < 0) wst = 0;
  const int oldlen = cs - wst;
  const long per = (long)oldlen * 16;   // 16 chunks of 8 along d
  const long total = per * NHEADS;
  for (long c = blockIdx.x * (long)blockDim.x + threadIdx.x; c < total;
       c += (long)gridDim.x * blockDim.x) {
    int n = (int)(c / per);
    long r = c - (long)n * per;
    int jo = (int)(r >> 4);
    int dc = ((int)r & 15) * 8;
    const float* s = kc + ((size_t)(wst + jo) * NHEADS + n) * HDIM + dc;
    float4 a = *(const float4*)s;
    float4 b = *(const float4*)(s + 4);
    uint4 o;
    o.x = (u32)f2bf(a.x) | ((u32)f2bf(a.y) << 16);
    o.y = (u32)f2bf(a.z) | ((u32)f2bf(a.w) << 16);
    o.z = (u32)f2bf(b.x) | ((u32)f2bf(b.y) << 16);
    o.w = (u32)f2bf(b.z) | ((u32)f2bf(b.w) << 16);
    *(uint4*)(K_all + ((size_t)n * KVcap + jo) * HDIM + dc) = o;
  }
}

// ---------------- old cache -> bf16 V^T window [n][d][jj], LDS tile transpose ----------------
// grid: (ceil(maxold/64), NHEADS). Coalesced float4 reads along d, LDS [64][130]
// (odd word stride -> conflict-free column gather), contiguous uint4 writes along j.
__launch_bounds__(256)
__global__ void k_build_vtold(const float* __restrict__ vc, u16* __restrict__ VT,
                              const int* __restrict__ csp, int S, int KVcap) {
  __shared__ u16 tile[64][130];
  const int cs = csp[0];
  const int ce = cs + S;
  int wst = ce - MAX_ATTN_W; if (wst < 0) wst = 0;
  const int oldlen = cs - wst;
  const int n = blockIdx.y;
  const int j0 = blockIdx.x * 64;
  if (j0 >= oldlen) return;
  const int tid = threadIdx.x;

  #pragma unroll
  for (int i = 0; i < 8; i++) {
    int idx = tid + 256 * i;
    int j = idx >> 5;
    int dc = (idx & 31) * 4;
    float4 v = make_float4(0.f, 0.f, 0.f, 0.f);
    if (j0 + j < oldlen)
      v = *(const float4*)(vc + ((size_t)(wst + j0 + j) * NHEADS + n) * HDIM + dc);
    u32 lo = (u32)f2bf(v.x) | ((u32)f2bf(v.y) << 16);
    u32 hi = (u32)f2bf(v.z) | ((u32)f2bf(v.w) << 16);
    *(u32*)&tile[j][dc] = lo;
    *(u32*)&tile[j][dc + 2] = hi;
  }
  __syncthreads();

  const int d = tid >> 1;
  const int jh = (tid & 1) * 32;
  alignas(16) u16 buf[32];
  #pragma unroll
  for (int j = 0; j < 32; j++) buf[j] = tile[jh + j][d];
  u16* dst = VT + ((size_t)n * HDIM + d) * KVcap + j0 + jh;
  if (j0 + jh + 32 <= oldlen) {
    #pragma unroll
    for (int c = 0; c < 4; c++)
      *(uint4*)(dst + c * 8) = *(const uint4*)&buf[c * 8];
  } else {
    for (int j = 0; j < 32 && j0 + jh + j < oldlen; j++) dst[j] = buf[j];
  }
}

// ---------------- bf16 GEMM: out[m][n] = sum_k A[m][k]*B[n][k] + bias[n] ----------------
__launch_bounds__(256)
__global__ void k_gemm_bt(const u16* __restrict__ A, const u16* __restrict__ B,
                          const float* __restrict__ bias, float* __restrict__ out,
                          int M, int N, int K) {
  __shared__ __align__(16) u16 Al[64][40];
  __shared__ __align__(16) u16 Bl[64][40];
  const int tid = threadIdx.x;
  const int w = tid >> 6, l = tid & 63, l15 = l & 15, g = l >> 4;
  const int wr = w >> 1, wc = w & 1;
  const int m0 = blockIdx.x * 64, n0 = blockIdx.y * 64;
  f32x4 acc[2][2] = {};
  const int row = tid >> 2, colc = (tid & 3) * 8;
  for (int k0 = 0; k0 < K; k0 += 32) {
    __syncthreads();
    uint4 av = make_uint4(0, 0, 0, 0);
    int gm = m0 + row;
    if (gm < M) av = *(const uint4*)(A + (size_t)gm * K + k0 + colc);
    *(uint4*)&Al[row][colc] = av;
    uint4 bv = *(const uint4*)(B + (size_t)(n0 + row) * K + k0 + colc);
    *(uint4*)&Bl[row][colc] = bv;
    __syncthreads();
    bf16x8 af[2], bfr[2];
    #pragma unroll
    for (int mt = 0; mt < 2; mt++) af[mt] = *(const bf16x8*)&Al[wr * 32 + mt * 16 + l15][g * 8];
    #pragma unroll
    for (int nt = 0; nt < 2; nt++) bfr[nt] = *(const bf16x8*)&Bl[wc * 32 + nt * 16 + l15][g * 8];
    #pragma unroll
    for (int mt = 0; mt < 2; mt++)
      #pragma unroll
      for (int nt = 0; nt < 2; nt++)
        acc[mt][nt] = __builtin_amdgcn_mfma_f32_16x16x32_bf16(af[mt], bfr[nt], acc[mt][nt], 0, 0, 0);
  }
  #pragma unroll
  for (int mt = 0; mt < 2; mt++)
    #pragma unroll
    for (int nt = 0; nt < 2; nt++)
      #pragma unroll
      for (int r = 0; r < 4; r++) {
        int mm = m0 + wr * 32 + mt * 16 + (g << 2) + r;
        int nn = n0 + wc * 32 + nt * 16 + l15;
        if (mm < M) out[(size_t)mm * N + nn] = acc[mt][nt][r] + bias[nn];
      }
}

// ---------------- fused QKV GEMM (3 weight matrices, one launch) ----------------
__launch_bounds__(256)
__global__ void k_gemm_qkv(const u16* __restrict__ A,
                           const u16* __restrict__ B0, const u16* __restrict__ B1,
                           const u16* __restrict__ B2,
                           const float* __restrict__ bias0, const float* __restrict__ bias1,
                           const float* __restrict__ bias2,
                           float* __restrict__ o0, float* __restrict__ o1, float* __restrict__ o2,
                           int M, int N, int K) {
  __shared__ __align__(16) u16 Al[64][40];
  __shared__ __align__(16) u16 Bl[64][40];
  const int nblk = N / 64;
  const int which = blockIdx.y / nblk;
  const int n0 = (blockIdx.y % nblk) * 64;
  const u16* B = (which == 0) ? B0 : ((which == 1) ? B1 : B2);
  const float* bias = (which == 0) ? bias0 : ((which == 1) ? bias1 : bias2);
  float* out = (which == 0) ? o0 : ((which == 1) ? o1 : o2);
  const int tid = threadIdx.x;
  const int w = tid >> 6, l = tid & 63, l15 = l & 15, g = l >> 4;
  const int wr = w >> 1, wc = w & 1;
  const int m0 = blockIdx.x * 64;
  f32x4 acc[2][2] = {};
  const int row = tid >> 2, colc = (tid & 3) * 8;
  for (int k0 = 0; k0 < K; k0 += 32) {
    __syncthreads();
    uint4 av = make_uint4(0, 0, 0, 0);
    int gm = m0 + row;
    if (gm < M) av = *(const uint4*)(A + (size_t)gm * K + k0 + colc);
    *(uint4*)&Al[row][colc] = av;
    uint4 bv = *(const uint4*)(B + (size_t)(n0 + row) * K + k0 + colc);
    *(uint4*)&Bl[row][colc] = bv;
    __syncthreads();
    bf16x8 af[2], bfr[2];
    #pragma unroll
    for (int mt = 0; mt < 2; mt++) af[mt] = *(const bf16x8*)&Al[wr * 32 + mt * 16 + l15][g * 8];
    #pragma unroll
    for (int nt = 0; nt < 2; nt++) bfr[nt] = *(const bf16x8*)&Bl[wc * 32 + nt * 16 + l15][g * 8];
    #pragma unroll
    for (int mt = 0; mt < 2; mt++)
      #pragma unroll
      for (int nt = 0; nt < 2; nt++)
        acc[mt][nt] = __builtin_amdgcn_mfma_f32_16x16x32_bf16(af[mt], bfr[nt], acc[mt][nt], 0, 0, 0);
  }
  #pragma unroll
  for (int mt = 0; mt < 2; mt++)
    #pragma unroll
    for (int nt = 0; nt < 2; nt++)
      #pragma unroll
      for (int r = 0; r < 4; r++) {
        int mm = m0 + wr * 32 + mt * 16 + (g << 2) + r;
        int nn = n0 + wc * 32 + nt * 16 + l15;
        if (mm < M) out[(size_t)mm * N + nn] = acc[mt][nt][r] + bias[nn];
      }
}

// ---------------- fused RMSNorm + RoPE + KV-window scatter ----------------
__launch_bounds__(256)
__global__ void k_norm_rope(const float* __restrict__ qp, const float* __restrict__ kp,
                            const float* __restrict__ vp, const float* __restrict__ gq,
                            const float* __restrict__ gk, const float* __restrict__ freqs,
                            const int* __restrict__ gs, const int* __restrict__ csp,
                            int S, int KVcap,
                            u16* __restrict__ rq, u16* __restrict__ K_all,
                            u16* __restrict__ VT) {
  const int t = blockIdx.x;
  const int tid = threadIdx.x;
  const float* q = qp + (size_t)t * MODEL_DIM;
  const float* k = kp + (size_t)t * MODEL_DIM;
  const float* v = vp + (size_t)t * MODEL_DIM;
  float sq = 0.f, sk = 0.f;
  for (int j = tid; j < MODEL_DIM; j += 256) {
    float a = q[j]; sq += a * a;
    float b = k[j]; sk += b * b;
  }
  #pragma unroll
  for (int off = 32; off > 0; off >>= 1) {
    sq += __shfl_down(sq, off, 64);
    sk += __shfl_down(sk, off, 64);
  }
  __shared__ float red[8];
  int wv_ = tid >> 6, l = tid & 63;
  if (l == 0) { red[wv_] = sq; red[4 + wv_] = sk; }
  __syncthreads();
  sq = red[0] + red[1] + red[2] + red[3];
  sk = red[4] + red[5] + red[6] + red[7];
  const float rq_s = rsqrtf(sq * (1.0f / MODEL_DIM) + 1e-6f);
  const float rk_s = rsqrtf(sk * (1.0f / MODEL_DIM) + 1e-6f);

  const int cs = csp[0];
  const int h = gs[1], ww = gs[2];
  const int hw = h * ww;
  const int sf = cs / hw;                 // start_frame
  const int fi = t / hw;
  const int rr = t - fi * hw;
  const int hi = rr / ww;
  const int wi = rr - hi * ww;
  const int ce = cs + S;
  int wst = ce - MAX_ATTN_W; if (wst < 0) wst = 0;
  const int jj = cs + t - wst;

  for (int p = tid; p < NHEADS * 64; p += 256) {
    int n = p >> 6, c = p & 63;
    int pos = (c < 22) ? (sf + fi) : ((c < 43) ? hi : wi);
    float cv = freqs[(pos * 64 + c) * 2];
    float sv = freqs[(pos * 64 + c) * 2 + 1];
    int j0 = n * HDIM + 2 * c;
    float qr = q[j0] * rq_s * gq[j0];
    float qi = q[j0 + 1] * rq_s * gq[j0 + 1];
    u32 oq = (u32)f2bf(qr * cv - qi * sv) | ((u32)f2bf(qr * sv + qi * cv) << 16);
    *(u32*)(rq + ((size_t)n * S + t) * HDIM + 2 * c) = oq;
    float kr = k[j0] * rk_s * gk[j0];
    float ki = k[j0 + 1] * rk_s * gk[j0 + 1];
    u32 ok = (u32)f2bf(kr * cv - ki * sv) | ((u32)f2bf(kr * sv + ki * cv) << 16);
    *(u32*)(K_all + ((size_t)n * KVcap + jj) * HDIM + 2 * c) = ok;
  }
  for (int j = tid; j < MODEL_DIM; j += 256) {
    int n = j >> 7, d = j & 127;
    VT[((size_t)n * HDIM + d) * KVcap + jj] = f2bf(v[j]);
  }
}

// ---------------- flash attention, split-K over the KV window ----------------
__launch_bounds__(256, 4)
__global__ void k_attn_split(const u16* __restrict__ rq, const u16* __restrict__ K_all,
                             const u16* __restrict__ VT,
                             u16* __restrict__ po, float* __restrict__ pm, float* __restrict__ pl,
                             const int* __restrict__ csp, int S, int KVcap) {
  __shared__ __align__(16) u16 Klds[64][132];
  __shared__ __align__(16) u16 Vlds[128][68];
  // P (bf16, [64][68]) overlays Klds: written only after a barrier that ends all K reads.
  u16 (*Plds)[68] = reinterpret_cast<u16(*)[68]>(&Klds[0][0]);

  const int tid = threadIdx.x;
  const int w = tid >> 6;
  const int l = tid & 63;
  const int l15 = l & 15;
  const int g = l >> 4;
  const int head = blockIdx.y;
  const int split = blockIdx.z;
  const int q0 = blockIdx.x * 64;

  const int cs = csp[0];
  const int ce = cs + S;
  int wst = ce - MAX_ATTN_W; if (wst < 0) wst = 0;
  const int KV = ce - wst;
  const int chunk = (((KV + NSPLIT - 1) / NSPLIT) + 63) & ~63;
  const int kstart = split * chunk;
  int kend = kstart + chunk; if (kend > KV) kend = KV;

  const size_t pbase = ((size_t)head * NSPLIT + split) * S;

  if (kstart >= kend) {
    #pragma unroll
    for (int r = 0; r < 4; r++) {
      int q = q0 + (w << 4) + (g << 2) + r;
      if (q < S && l15 == 0) { pm[pbase + q] = -3.0e38f; pl[pbase + q] = 0.f; }
    }
    return;
  }

  // Q fragments held in registers (A-frag: row=l&15, k=(l>>4)*8+i)
  bf16x8 qf[4];
  {
    int qrow = q0 + (w << 4) + l15;
    if (qrow < S) {
      const u16* qp = rq + ((size_t)head * S + qrow) * HDIM + g * 8;
      #pragma unroll
      for (int ds = 0; ds < 4; ds++) qf[ds] = *(const bf16x8*)(qp + ds * 32);
    } else {
      bf16x8 z;
      #pragma unroll
      for (int i = 0; i < 8; i++) z[i] = (__bf16)0.0f;
      #pragma unroll
      for (int ds = 0; ds < 4; ds++) qf[ds] = z;
    }
  }

  f32x4 o[8];
  #pragma unroll
  for (int dt = 0; dt < 8; dt++) o[dt] = (f32x4){0.f, 0.f, 0.f, 0.f};
  float m[4], lsum[4];
  #pragma unroll
  for (int r = 0; r < 4; r++) { m[r] = -3.0e38f; lsum[r] = 0.f; }

  const u16* Kh = K_all + (size_t)head * KVcap * HDIM;
  const u16* Vh = VT + (size_t)head * HDIM * KVcap;
  const float rscale = 0.08838834764831845f;   // 1/sqrt(128)

  const int ntiles = (kend - kstart + 63) >> 6;
  for (int t = 0; t < ntiles; t++) {
    const int key0 = kstart + (t << 6);
    __syncthreads();   // prev tile's P reads (Klds overlay) + V reads done
    #pragma unroll
    for (int i = 0; i < 4; i++) {
      int cid = tid + 256 * i;
      int krow = cid >> 4;
      int col = (cid & 15) * 8;
      int gk_ = key0 + krow;
      uint4 kv4 = make_uint4(0, 0, 0, 0);
      if (gk_ < kend) kv4 = *(const uint4*)(Kh + (size_t)gk_ * HDIM + col);
      *(uint4*)&Klds[krow][col] = kv4;
    }
    #pragma unroll
    for (int i = 0; i < 4; i++) {
      int cid = tid + 256 * i;
      int d = cid >> 3;
      int kc = (cid & 7) * 8;
      const u16* src = Vh + (size_t)d * KVcap + key0 + kc;
      uint4 vv4;
      if (key0 + kc + 8 <= kend) {
        vv4 = *(const uint4*)src;
      } else {
        alignas(16) u16 tmp[8];
        #pragma unroll
        for (int j = 0; j < 8; j++) tmp[j] = (key0 + kc + j < kend) ? src[j] : (u16)0;
        vv4 = *(const uint4*)tmp;
      }
      *(uint4*)&Vlds[d][kc] = vv4;
    }
    __syncthreads();

    // QK^T : D[row=q][col=key]
    f32x4 s[4];
    #pragma unroll
    for (int kt = 0; kt < 4; kt++) {
      s[kt] = (f32x4){0.f, 0.f, 0.f, 0.f};
      #pragma unroll
      for (int ds = 0; ds < 4; ds++) {
        bf16x8 kf = *(const bf16x8*)&Klds[kt * 16 + l15][ds * 32 + g * 8];
        s[kt] = __builtin_amdgcn_mfma_f32_16x16x32_bf16(qf[ds], kf, s[kt], 0, 0, 0);
      }
    }

    // online softmax in registers
    float tmax[4] = {-3.0e38f, -3.0e38f, -3.0e38f, -3.0e38f};
    #pragma unroll
    for (int kt = 0; kt < 4; kt++) {
      int key = key0 + kt * 16 + l15;
      bool okk = key < kend;
      #pragma unroll
      for (int r = 0; r < 4; r++) {
        float v = s[kt][r] * rscale;
        v = okk ? v : -3.0e38f;
        s[kt][r] = v;
        tmax[r] = fmaxf(tmax[r], v);
      }
    }
    #pragma unroll
    for (int off = 1; off < 16; off <<= 1)
      #pragma unroll
      for (int r = 0; r < 4; r++)
        tmax[r] = fmaxf(tmax[r], __shfl_xor(tmax[r], off, 16));
    float alpha[4];
    #pragma unroll
    for (int r = 0; r < 4; r++) {
      float nm = fmaxf(m[r], tmax[r]);
      alpha[r] = __expf(m[r] - nm);
      m[r] = nm;
    }
    float rs[4] = {0.f, 0.f, 0.f, 0.f};
    u16 pu[4][4];
    #pragma unroll
    for (int kt = 0; kt < 4; kt++)
      #pragma unroll
      for (int r = 0; r < 4; r++) {
        float p = __expf(s[kt][r] - m[r]);
        rs[r] += p;
        pu[kt][r] = f2bf(p);
      }
    #pragma unroll
    for (int off = 1; off < 16; off <<= 1)
      #pragma unroll
      for (int r = 0; r < 4; r++)
        rs[r] += __shfl_xor(rs[r], off, 16);
    #pragma unroll
    for (int r = 0; r < 4; r++) lsum[r] = lsum[r] * alpha[r] + rs[r];
    #pragma unroll
    for (int dt = 0; dt < 8; dt++)
      #pragma unroll
      for (int r = 0; r < 4; r++) o[dt][r] *= alpha[r];

    __syncthreads();   // all waves done reading Klds -> safe to overwrite as P
    #pragma unroll
    for (int kt = 0; kt < 4; kt++)
      #pragma unroll
      for (int r = 0; r < 4; r++)
        Plds[(w << 4) + (g << 2) + r][kt * 16 + l15] = pu[kt][r];

    bf16x8 pf[2];
    #pragma unroll
    for (int c = 0; c < 2; c++)
      pf[c] = *(const bf16x8*)&Plds[(w << 4) + l15][c * 32 + g * 8];

    // PV: O[q][d] += P[q][key] * V[key][d]   (B-frag from V^T tile)
    #pragma unroll
    for (int dt = 0; dt < 8; dt++) {
      #pragma unroll
      for (int c = 0; c < 2; c++) {
        bf16x8 vf = *(const bf16x8*)&Vlds[dt * 16 + l15][c * 32 + g * 8];
        o[dt] = __builtin_amdgcn_mfma_f32_16x16x32_bf16(pf[c], vf, o[dt], 0, 0, 0);
      }
    }
  }

  // epilogue: per-split normalized partial (bf16) + m/l scalars
  #pragma unroll
  for (int r = 0; r < 4; r++) {
    int q = q0 + (w << 4) + (g << 2) + r;
    if (q < S) {
      float rl = (lsum[r] > 0.f) ? (1.0f / lsum[r]) : 0.f;
      #pragma unroll
      for (int dt = 0; dt < 8; dt++)
        po[(pbase + q) * HDIM + dt * 16 + l15] = f2bf(o[dt][r] * rl);
      if (l15 == 0) { pm[pbase + q] = m[r]; pl[pbase + q] = lsum[r]; }
    }
  }
}

// ---------------- combine split-K partials ----------------
__global__ void k_attn_reduce(const u16* __restrict__ po, const float* __restrict__ pm,
                              const float* __restrict__ pl, u16* __restrict__ attn_out,
                              int S) {
  const int t = blockIdx.x;
  const int h = blockIdx.y;
  const int d = threadIdx.x;   // 128 threads
  float ms[NSPLIT];
  float M = -3.0e38f;
  #pragma unroll
  for (int s = 0; s < NSPLIT; s++) {
    ms[s] = pm[((size_t)h * NSPLIT + s) * S + t];
    M = fmaxf(M, ms[s]);
  }
  float L = 0.f, acc = 0.f;
  #pragma unroll
  for (int s = 0; s < NSPLIT; s++) {
    float wgt = __expf(ms[s] - M) * pl[((size_t)h * NSPLIT + s) * S + t];
    L += wgt;
    acc += wgt * bf2f(po[(((size_t)h * NSPLIT + s) * S + t) * HDIM + d]);
  }
  attn_out[(size_t)t * MODEL_DIM + h * HDIM + d] = f2bf(acc / L);
}

extern "C" void kernel_launch(void* const* d_in, const int* in_sizes, int n_in,
                              void* d_out, int out_size, void* d_ws, size_t ws_size,
                              hipStream_t stream) {
  (void)n_in; (void)out_size; (void)ws_size;
  const float* x  = (const float*)d_in[0];
  const float* wq = (const float*)d_in[1];
  const float* bq = (const float*)d_in[2];
  const float* wk = (const float*)d_in[3];
  const float* bk = (const float*)d_in[4];
  const float* wv = (const float*)d_in[5];
  const float* bv = (const float*)d_in[6];
  const float* wo = (const float*)d_in[7];
  const float* bo = (const float*)d_in[8];
  const float* gq = (const float*)d_in[9];
  const float* gk = (const float*)d_in[10];
  const float* freqs = (const float*)d_in[11];
  const float* k_cache = (const float*)d_in[12];
  const float* v_cache = (const float*)d_in[13];
  const int* gs  = (const int*)d_in[14];
  const int* csp = (const int*)d_in[15];

  const int S = in_sizes[0] / MODEL_DIM;
  const int CACHE = in_sizes[12] / (NHEADS * HDIM);
  const int KVcap = (CACHE < MAX_ATTN_W) ? CACHE : MAX_ATTN_W;

  char* ws = (char*)d_ws;
  size_t off = 0;
  auto alloc = [&](size_t bytes) {
    char* p = ws + off;
    off += (bytes + 255) & ~(size_t)255;
    return p;
  };
  u16* xb   = (u16*)alloc((size_t)S * MODEL_DIM * 2);
  u16* wqb  = (u16*)alloc((size_t)MODEL_DIM * MODEL_DIM * 2);
  u16* wkb  = (u16*)alloc((size_t)MODEL_DIM * MODEL_DIM * 2);
  u16* wvb  = (u16*)alloc((size_t)MODEL_DIM * MODEL_DIM * 2);
  u16* wob  = (u16*)alloc((size_t)MODEL_DIM * MODEL_DIM * 2);
  float* q_pre = (float*)alloc((size_t)S * MODEL_DIM * 4);
  float* k_pre = (float*)alloc((size_t)S * MODEL_DIM * 4);
  float* v_pre = (float*)alloc((size_t)S * MODEL_DIM * 4);
  u16* rqb   = (u16*)alloc((size_t)NHEADS * S * HDIM * 2);
  u16* K_all = (u16*)alloc((size_t)NHEADS * KVcap * HDIM * 2);
  u16* VT    = (u16*)alloc((size_t)NHEADS * HDIM * KVcap * 2);
  u16* attn_o = (u16*)alloc((size_t)S * MODEL_DIM * 2);
  u16* po    = (u16*)alloc((size_t)NHEADS * NSPLIT * S * HDIM * 2);
  float* pm  = (float*)alloc((size_t)NHEADS * NSPLIT * S * 4);
  float* pl  = (float*)alloc((size_t)NHEADS * NSPLIT * S * 4);

  const int nx4 = S * MODEL_DIM / 4;
  const int nw4 = MODEL_DIM * MODEL_DIM / 4;
  hipLaunchKernelGGL(k_conv_bf16, dim3((nx4 + 255) / 256), dim3(256), 0, stream, x, xb, nx4);
  hipLaunchKernelGGL(k_conv_bf16_w4, dim3((nw4 + 255) / 256, 4), dim3(256), 0, stream,
                     wq, wk, wv, wo, wqb, wkb, wvb, wob, nw4);

  hipLaunchKernelGGL(k_build_kold, dim3(2048), dim3(256), 0, stream, k_cache, K_all, csp, S, KVcap);
  // grid covers the max possible window; blocks beyond oldlen early-exit (cs is device-side)
  hipLaunchKernelGGL(k_build_vtold, dim3((KVcap + 63) / 64, NHEADS), dim3(256), 0, stream,
                     v_cache, VT, csp, S, KVcap);

  hipLaunchKernelGGL(k_gemm_qkv, dim3((S + 63) / 64, 3 * MODEL_DIM / 64), dim3(256), 0, stream,
                     xb, wqb, wkb, wvb, bq, bk, bv, q_pre, k_pre, v_pre, S, MODEL_DIM, MODEL_DIM);

  hipLaunchKernelGGL(k_norm_rope, dim3(S), dim3(256), 0, stream,
                     q_pre, k_pre, v_pre, gq, gk, freqs, gs, csp, S, KVcap, rqb, K_all, VT);

  hipLaunchKernelGGL(k_attn_split, dim3((S + 63) / 64, NHEADS, NSPLIT), dim3(256), 0, stream,
                     rqb, K_all, VT, po, pm, pl, csp, S, KVcap);

  hipLaunchKernelGGL(k_attn_reduce, dim3(S, NHEADS), dim3(128), 0, stream, po, pm, pl, attn_o, S);

  hipLaunchKernelGGL(k_gemm_bt, dim3((S + 63) / 64, MODEL_DIM / 64), dim3(256), 0, stream,
                     attn_o, wob, bo, (float*)d_out, S, MODEL_DIM, MODEL_DIM);
}

// Round 4
// 369.901 us; speedup vs baseline: 2.7639x; 1.0227x over previous
//
#include <hip/hip_runtime.h>

#define NHEADS 12
#define HDIM 128
#define MODEL_DIM 1536
#define MAX_ATTN_W 13200
#define NSPLIT 12

typedef unsigned short u16;
typedef unsigned int u32;
typedef float f32x4 __attribute__((ext_vector_type(4)));
typedef __bf16 bf16x8 __attribute__((ext_vector_type(8)));

static __device__ __forceinline__ u16 f2bf(float f) {
  union { __bf16 h; u16 u; } cv;
  cv.h = (__bf16)f;
  return cv.u;
}
static __device__ __forceinline__ float bf2f(u16 u) {
  union { u32 u; float f; } cv;
  cv.u = ((u32)u) << 16;
  return cv.f;
}

// ---------------- fp32 -> bf16 convert (single buffer) ----------------
__global__ void k_conv_bf16(const float* __restrict__ src, u16* __restrict__ dst, int n4) {
  int i = blockIdx.x * blockDim.x + threadIdx.x;
  if (i >= n4) return;
  float4 v = ((const float4*)src)[i];
  u32 lo = (u32)f2bf(v.x) | ((u32)f2bf(v.y) << 16);
  u32 hi = (u32)f2bf(v.z) | ((u32)f2bf(v.w) << 16);
  ((uint2*)dst)[i] = make_uint2(lo, hi);
}

// ---------------- fp32 -> bf16 convert, 4 weight matrices in one launch ----------------
__global__ void k_conv_bf16_w4(const float* __restrict__ s0, const float* __restrict__ s1,
                               const float* __restrict__ s2, const float* __restrict__ s3,
                               u16* __restrict__ d0, u16* __restrict__ d1,
                               u16* __restrict__ d2, u16* __restrict__ d3, int n4) {
  int i = blockIdx.x * blockDim.x + threadIdx.x;
  if (i >= n4) return;
  const int which = blockIdx.y;
  const float* src = (which == 0) ? s0 : (which == 1) ? s1 : (which == 2) ? s2 : s3;
  u16* dst = (which == 0) ? d0 : (which == 1) ? d1 : (which == 2) ? d2 : d3;
  float4 v = ((const float4*)src)[i];
  u32 lo = (u32)f2bf(v.x) | ((u32)f2bf(v.y) << 16);
  u32 hi = (u32)f2bf(v.z) | ((u32)f2bf(v.w) << 16);
  ((uint2*)dst)[i] = make_uint2(lo, hi);
}

// ---------------- old cache -> bf16 K window [n][jj][d] (coalesced both sides) ----------------
__global__ void k_build_kold(const float* __restrict__ kc, u16* __restrict__ K_all,
                             const int* __restrict__ csp, int S, int KVcap) {
  const int cs = csp[0];
  const int ce = cs + S;
  int wst = ce - MAX_ATTN_W; if (wst < 0) wst = 0;
  const int oldlen = cs - wst;
  const long per = (long)oldlen * 16;   // 16 chunks of 8 along d
  const long total = per * NHEADS;
  for (long c = blockIdx.x * (long)blockDim.x + threadIdx.x; c < total;
       c += (long)gridDim.x * blockDim.x) {
    int n = (int)(c / per);
    long r = c - (long)n * per;
    int jo = (int)(r >> 4);
    int dc = ((int)r & 15) * 8;
    const float* s = kc + ((size_t)(wst + jo) * NHEADS + n) * HDIM + dc;
    float4 a = *(const float4*)s;
    float4 b = *(const float4*)(s + 4);
    uint4 o;
    o.x = (u32)f2bf(a.x) | ((u32)f2bf(a.y) << 16);
    o.y = (u32)f2bf(a.z) | ((u32)f2bf(a.w) << 16);
    o.z = (u32)f2bf(b.x) | ((u32)f2bf(b.y) << 16);
    o.w = (u32)f2bf(b.z) | ((u32)f2bf(b.w) << 16);
    *(uint4*)(K_all + ((size_t)n * KVcap + jo) * HDIM + dc) = o;
  }
}

// ---------------- old cache -> bf16 V^T window [n][d][jj], LDS tile transpose ----------------
__launch_bounds__(256)
__global__ void k_build_vtold(const float* __restrict__ vc, u16* __restrict__ VT,
                              const int* __restrict__ csp, int S, int KVcap) {
  __shared__ u16 tile[64][130];
  const int cs = csp[0];
  const int ce = cs + S;
  int wst = ce - MAX_ATTN_W; if (wst < 0) wst = 0;
  const int oldlen = cs - wst;
  const int n = blockIdx.y;
  const int j0 = blockIdx.x * 64;
  if (j0 >= oldlen) return;
  const int tid = threadIdx.x;

  #pragma unroll
  for (int i = 0; i < 8; i++) {
    int idx = tid + 256 * i;
    int j = idx >> 5;
    int dc = (idx & 31) * 4;
    float4 v = make_float4(0.f, 0.f, 0.f, 0.f);
    if (j0 + j < oldlen)
      v = *(const float4*)(vc + ((size_t)(wst + j0 + j) * NHEADS + n) * HDIM + dc);
    u32 lo = (u32)f2bf(v.x) | ((u32)f2bf(v.y) << 16);
    u32 hi = (u32)f2bf(v.z) | ((u32)f2bf(v.w) << 16);
    *(u32*)&tile[j][dc] = lo;
    *(u32*)&tile[j][dc + 2] = hi;
  }
  __syncthreads();

  const int d = tid >> 1;
  const int jh = (tid & 1) * 32;
  alignas(16) u16 buf[32];
  #pragma unroll
  for (int j = 0; j < 32; j++) buf[j] = tile[jh + j][d];
  u16* dst = VT + ((size_t)n * HDIM + d) * KVcap + j0 + jh;
  if (j0 + jh + 32 <= oldlen) {
    #pragma unroll
    for (int c = 0; c < 4; c++)
      *(uint4*)(dst + c * 8) = *(const uint4*)&buf[c * 8];
  } else {
    for (int j = 0; j < 32 && j0 + jh + j < oldlen; j++) dst[j] = buf[j];
  }
}

// ---------------- bf16 GEMM: out[m][n] = sum_k A[m][k]*B[n][k] + bias[n] ----------------
__launch_bounds__(256)
__global__ void k_gemm_bt(const u16* __restrict__ A, const u16* __restrict__ B,
                          const float* __restrict__ bias, float* __restrict__ out,
                          int M, int N, int K) {
  __shared__ __align__(16) u16 Al[64][40];
  __shared__ __align__(16) u16 Bl[64][40];
  const int tid = threadIdx.x;
  const int w = tid >> 6, l = tid & 63, l15 = l & 15, g = l >> 4;
  const int wr = w >> 1, wc = w & 1;
  const int m0 = blockIdx.x * 64, n0 = blockIdx.y * 64;
  f32x4 acc[2][2] = {};
  const int row = tid >> 2, colc = (tid & 3) * 8;
  for (int k0 = 0; k0 < K; k0 += 32) {
    __syncthreads();
    uint4 av = make_uint4(0, 0, 0, 0);
    int gm = m0 + row;
    if (gm < M) av = *(const uint4*)(A + (size_t)gm * K + k0 + colc);
    *(uint4*)&Al[row][colc] = av;
    uint4 bv = *(const uint4*)(B + (size_t)(n0 + row) * K + k0 + colc);
    *(uint4*)&Bl[row][colc] = bv;
    __syncthreads();
    bf16x8 af[2], bfr[2];
    #pragma unroll
    for (int mt = 0; mt < 2; mt++) af[mt] = *(const bf16x8*)&Al[wr * 32 + mt * 16 + l15][g * 8];
    #pragma unroll
    for (int nt = 0; nt < 2; nt++) bfr[nt] = *(const bf16x8*)&Bl[wc * 32 + nt * 16 + l15][g * 8];
    #pragma unroll
    for (int mt = 0; mt < 2; mt++)
      #pragma unroll
      for (int nt = 0; nt < 2; nt++)
        acc[mt][nt] = __builtin_amdgcn_mfma_f32_16x16x32_bf16(af[mt], bfr[nt], acc[mt][nt], 0, 0, 0);
  }
  #pragma unroll
  for (int mt = 0; mt < 2; mt++)
    #pragma unroll
    for (int nt = 0; nt < 2; nt++)
      #pragma unroll
      for (int r = 0; r < 4; r++) {
        int mm = m0 + wr * 32 + mt * 16 + (g << 2) + r;
        int nn = n0 + wc * 32 + nt * 16 + l15;
        if (mm < M) out[(size_t)mm * N + nn] = acc[mt][nt][r] + bias[nn];
      }
}

// ---------------- fused QKV GEMM (3 weight matrices, one launch) ----------------
__launch_bounds__(256)
__global__ void k_gemm_qkv(const u16* __restrict__ A,
                           const u16* __restrict__ B0, const u16* __restrict__ B1,
                           const u16* __restrict__ B2,
                           const float* __restrict__ bias0, const float* __restrict__ bias1,
                           const float* __restrict__ bias2,
                           float* __restrict__ o0, float* __restrict__ o1, float* __restrict__ o2,
                           int M, int N, int K) {
  __shared__ __align__(16) u16 Al[64][40];
  __shared__ __align__(16) u16 Bl[64][40];
  const int nblk = N / 64;
  const int which = blockIdx.y / nblk;
  const int n0 = (blockIdx.y % nblk) * 64;
  const u16* B = (which == 0) ? B0 : ((which == 1) ? B1 : B2);
  const float* bias = (which == 0) ? bias0 : ((which == 1) ? bias1 : bias2);
  float* out = (which == 0) ? o0 : ((which == 1) ? o1 : o2);
  const int tid = threadIdx.x;
  const int w = tid >> 6, l = tid & 63, l15 = l & 15, g = l >> 4;
  const int wr = w >> 1, wc = w & 1;
  const int m0 = blockIdx.x * 64;
  f32x4 acc[2][2] = {};
  const int row = tid >> 2, colc = (tid & 3) * 8;
  for (int k0 = 0; k0 < K; k0 += 32) {
    __syncthreads();
    uint4 av = make_uint4(0, 0, 0, 0);
    int gm = m0 + row;
    if (gm < M) av = *(const uint4*)(A + (size_t)gm * K + k0 + colc);
    *(uint4*)&Al[row][colc] = av;
    uint4 bv = *(const uint4*)(B + (size_t)(n0 + row) * K + k0 + colc);
    *(uint4*)&Bl[row][colc] = bv;
    __syncthreads();
    bf16x8 af[2], bfr[2];
    #pragma unroll
    for (int mt = 0; mt < 2; mt++) af[mt] = *(const bf16x8*)&Al[wr * 32 + mt * 16 + l15][g * 8];
    #pragma unroll
    for (int nt = 0; nt < 2; nt++) bfr[nt] = *(const bf16x8*)&Bl[wc * 32 + nt * 16 + l15][g * 8];
    #pragma unroll
    for (int mt = 0; mt < 2; mt++)
      #pragma unroll
      for (int nt = 0; nt < 2; nt++)
        acc[mt][nt] = __builtin_amdgcn_mfma_f32_16x16x32_bf16(af[mt], bfr[nt], acc[mt][nt], 0, 0, 0);
  }
  #pragma unroll
  for (int mt = 0; mt < 2; mt++)
    #pragma unroll
    for (int nt = 0; nt < 2; nt++)
      #pragma unroll
      for (int r = 0; r < 4; r++) {
        int mm = m0 + wr * 32 + mt * 16 + (g << 2) + r;
        int nn = n0 + wc * 32 + nt * 16 + l15;
        if (mm < M) out[(size_t)mm * N + nn] = acc[mt][nt][r] + bias[nn];
      }
}

// ---------------- fused RMSNorm + RoPE + KV-window scatter ----------------
__launch_bounds__(256)
__global__ void k_norm_rope(const float* __restrict__ qp, const float* __restrict__ kp,
                            const float* __restrict__ vp, const float* __restrict__ gq,
                            const float* __restrict__ gk, const float* __restrict__ freqs,
                            const int* __restrict__ gs, const int* __restrict__ csp,
                            int S, int KVcap,
                            u16* __restrict__ rq, u16* __restrict__ K_all,
                            u16* __restrict__ VT) {
  const int t = blockIdx.x;
  const int tid = threadIdx.x;
  const float* q = qp + (size_t)t * MODEL_DIM;
  const float* k = kp + (size_t)t * MODEL_DIM;
  const float* v = vp + (size_t)t * MODEL_DIM;
  float sq = 0.f, sk = 0.f;
  for (int j = tid; j < MODEL_DIM; j += 256) {
    float a = q[j]; sq += a * a;
    float b = k[j]; sk += b * b;
  }
  #pragma unroll
  for (int off = 32; off > 0; off >>= 1) {
    sq += __shfl_down(sq, off, 64);
    sk += __shfl_down(sk, off, 64);
  }
  __shared__ float red[8];
  int wv_ = tid >> 6, l = tid & 63;
  if (l == 0) { red[wv_] = sq; red[4 + wv_] = sk; }
  __syncthreads();
  sq = red[0] + red[1] + red[2] + red[3];
  sk = red[4] + red[5] + red[6] + red[7];
  const float rq_s = rsqrtf(sq * (1.0f / MODEL_DIM) + 1e-6f);
  const float rk_s = rsqrtf(sk * (1.0f / MODEL_DIM) + 1e-6f);

  const int cs = csp[0];
  const int h = gs[1], ww = gs[2];
  const int hw = h * ww;
  const int sf = cs / hw;                 // start_frame
  const int fi = t / hw;
  const int rr = t - fi * hw;
  const int hi = rr / ww;
  const int wi = rr - hi * ww;
  const int ce = cs + S;
  int wst = ce - MAX_ATTN_W; if (wst < 0) wst = 0;
  const int jj = cs + t - wst;

  for (int p = tid; p < NHEADS * 64; p += 256) {
    int n = p >> 6, c = p & 63;
    int pos = (c < 22) ? (sf + fi) : ((c < 43) ? hi : wi);
    float cv = freqs[(pos * 64 + c) * 2];
    float sv = freqs[(pos * 64 + c) * 2 + 1];
    int j0 = n * HDIM + 2 * c;
    float qr = q[j0] * rq_s * gq[j0];
    float qi = q[j0 + 1] * rq_s * gq[j0 + 1];
    u32 oq = (u32)f2bf(qr * cv - qi * sv) | ((u32)f2bf(qr * sv + qi * cv) << 16);
    *(u32*)(rq + ((size_t)n * S + t) * HDIM + 2 * c) = oq;
    float kr = k[j0] * rk_s * gk[j0];
    float ki = k[j0 + 1] * rk_s * gk[j0 + 1];
    u32 ok = (u32)f2bf(kr * cv - ki * sv) | ((u32)f2bf(kr * sv + ki * cv) << 16);
    *(u32*)(K_all + ((size_t)n * KVcap + jj) * HDIM + 2 * c) = ok;
  }
  for (int j = tid; j < MODEL_DIM; j += 256) {
    int n = j >> 7, d = j & 127;
    VT[((size_t)n * HDIM + d) * KVcap + jj] = f2bf(v[j]);
  }
}

// ---------------- flash attention, split-K, swapped-QK + register prefetch ----------------
// S^T = mfma(K,Q): lane(g,l15): s[kt][r] = S[key=16kt+4g+r][q=l15]. Softmax per q column:
// 15 in-lane ops + 2 shfl_xor. O^T = mfma(V^T, P): o[dt][r] = O[q=l15][d=dt*16+4g+r].
// Base-2 exponent domain throughout (pm stores log2-max; reduce uses exp2f).
__launch_bounds__(256, 3)
__global__ void k_attn_split(const u16* __restrict__ rq, const u16* __restrict__ K_all,
                             const u16* __restrict__ VT,
                             u16* __restrict__ po, float* __restrict__ pm, float* __restrict__ pl,
                             const int* __restrict__ csp, int S, int KVcap) {
  __shared__ __align__(16) u16 Klds[64][132];
  __shared__ __align__(16) u16 Vlds[128][68];
  __shared__ __align__(16) u16 Plds[64][68];

  const int tid = threadIdx.x;
  const int w = tid >> 6;
  const int l = tid & 63;
  const int l15 = l & 15;
  const int g = l >> 4;
  const int head = blockIdx.y;
  const int split = blockIdx.z;
  const int q0 = blockIdx.x * 64;

  const int cs = csp[0];
  const int ce = cs + S;
  int wst = ce - MAX_ATTN_W; if (wst < 0) wst = 0;
  const int KV = ce - wst;
  const int chunk = (((KV + NSPLIT - 1) / NSPLIT) + 63) & ~63;
  const int kstart = split * chunk;
  int kend = kstart + chunk; if (kend > KV) kend = KV;

  const size_t pbase = ((size_t)head * NSPLIT + split) * S;
  const int qrow = q0 + (w << 4) + l15;

  if (kstart >= kend) {
    if (qrow < S && l < 16) { pm[pbase + qrow] = -3.0e38f; pl[pbase + qrow] = 0.f; }
    return;
  }

  // Q fragments in registers: lane provides Q[q=l15][k=g*8+i] (B-frag for swapped QK)
  bf16x8 qf[4];
  {
    if (qrow < S) {
      const u16* qp = rq + ((size_t)head * S + qrow) * HDIM + g * 8;
      #pragma unroll
      for (int ds = 0; ds < 4; ds++) qf[ds] = *(const bf16x8*)(qp + ds * 32);
    } else {
      bf16x8 z;
      #pragma unroll
      for (int i = 0; i < 8; i++) z[i] = (__bf16)0.0f;
      #pragma unroll
      for (int ds = 0; ds < 4; ds++) qf[ds] = z;
    }
  }

  f32x4 o[8];
  #pragma unroll
  for (int dt = 0; dt < 8; dt++) o[dt] = (f32x4){0.f, 0.f, 0.f, 0.f};
  float m_ = -3.0e38f, lsum_ = 0.f;

  const u16* Kh = K_all + (size_t)head * KVcap * HDIM;
  const u16* Vh = VT + (size_t)head * HDIM * KVcap;
  const float sc2 = 0.12751744f;   // (1/sqrt(128)) * log2(e)

  uint4 kr[4], vr[4];
  auto load_tile = [&](int key0) {
    #pragma unroll
    for (int i = 0; i < 4; i++) {
      int cid = tid + 256 * i;
      int krow = cid >> 4;
      int col = (cid & 15) * 8;
      int gk_ = key0 + krow;
      kr[i] = make_uint4(0, 0, 0, 0);
      if (gk_ < kend) kr[i] = *(const uint4*)(Kh + (size_t)gk_ * HDIM + col);
    }
    #pragma unroll
    for (int i = 0; i < 4; i++) {
      int cid = tid + 256 * i;
      int d = cid >> 3;
      int kc = (cid & 7) * 8;
      const u16* src = Vh + (size_t)d * KVcap + key0 + kc;
      if (key0 + kc + 8 <= kend) {
        vr[i] = *(const uint4*)src;
      } else {
        alignas(16) u16 tmp[8];
        #pragma unroll
        for (int j = 0; j < 8; j++) tmp[j] = (key0 + kc + j < kend) ? src[j] : (u16)0;
        vr[i] = *(const uint4*)tmp;
      }
    }
  };

  const int ntiles = (kend - kstart + 63) >> 6;
  load_tile(kstart);

  for (int t = 0; t < ntiles; t++) {
    const int key0 = kstart + (t << 6);
    __syncthreads();   // previous tile's K/V LDS reads done (cross-wave)
    #pragma unroll
    for (int i = 0; i < 4; i++) {
      int cid = tid + 256 * i;
      *(uint4*)&Klds[cid >> 4][(cid & 15) * 8] = kr[i];
    }
    #pragma unroll
    for (int i = 0; i < 4; i++) {
      int cid = tid + 256 * i;
      *(uint4*)&Vlds[cid >> 3][(cid & 7) * 8] = vr[i];
    }
    if (t + 1 < ntiles) load_tile(key0 + 64);   // prefetch overlaps compute below
    __syncthreads();

    // QK^T swapped: D = S^T[key][q]
    f32x4 s[4];
    #pragma unroll
    for (int kt = 0; kt < 4; kt++) {
      s[kt] = (f32x4){0.f, 0.f, 0.f, 0.f};
      #pragma unroll
      for (int ds = 0; ds < 4; ds++) {
        bf16x8 kf = *(const bf16x8*)&Klds[kt * 16 + l15][ds * 32 + g * 8];
        s[kt] = __builtin_amdgcn_mfma_f32_16x16x32_bf16(kf, qf[ds], s[kt], 0, 0, 0);
      }
    }

    // scale to base-2 domain + mask; in-lane max over 16 keys
    float tm = -3.0e38f;
    #pragma unroll
    for (int kt = 0; kt < 4; kt++) {
      #pragma unroll
      for (int r = 0; r < 4; r++) {
        int key = key0 + kt * 16 + (g << 2) + r;
        float v = s[kt][r] * sc2;
        v = (key < kend) ? v : -3.0e38f;
        s[kt][r] = v;
        tm = fmaxf(tm, v);
      }
    }
    tm = fmaxf(tm, __shfl_xor(tm, 16, 64));
    tm = fmaxf(tm, __shfl_xor(tm, 32, 64));
    float nm = fmaxf(m_, tm);
    float alpha = exp2f(m_ - nm);
    m_ = nm;

    float rs = 0.f;
    u32 pk[4][2];
    #pragma unroll
    for (int kt = 0; kt < 4; kt++) {
      #pragma unroll
      for (int hh = 0; hh < 2; hh++) {
        float p0 = exp2f(s[kt][2 * hh] - m_);
        float p1 = exp2f(s[kt][2 * hh + 1] - m_);
        rs += p0 + p1;
        pk[kt][hh] = (u32)f2bf(p0) | ((u32)f2bf(p1) << 16);
      }
    }
    rs += __shfl_xor(rs, 16, 64);
    rs += __shfl_xor(rs, 32, 64);
    lsum_ = lsum_ * alpha + rs;

    // P[q][key] into per-wave LDS region (own rows; in-wave DS ordering suffices)
    #pragma unroll
    for (int kt = 0; kt < 4; kt++) {
      #pragma unroll
      for (int hh = 0; hh < 2; hh++)
        *(u32*)&Plds[(w << 4) + l15][kt * 16 + (g << 2) + 2 * hh] = pk[kt][hh];
    }

    #pragma unroll
    for (int dt = 0; dt < 8; dt++) {
      o[dt][0] *= alpha; o[dt][1] *= alpha; o[dt][2] *= alpha; o[dt][3] *= alpha;
    }

    // PV swapped: O^T = V^T * P  (A=vf, B=pf)
    bf16x8 pf[2];
    #pragma unroll
    for (int c = 0; c < 2; c++)
      pf[c] = *(const bf16x8*)&Plds[(w << 4) + l15][c * 32 + g * 8];
    #pragma unroll
    for (int dt = 0; dt < 8; dt++) {
      #pragma unroll
      for (int c = 0; c < 2; c++) {
        bf16x8 vf = *(const bf16x8*)&Vlds[dt * 16 + l15][c * 32 + g * 8];
        o[dt] = __builtin_amdgcn_mfma_f32_16x16x32_bf16(vf, pf[c], o[dt], 0, 0, 0);
      }
    }
  }

  // epilogue: lane(g,l15): q=qrow, d = dt*16 + 4g + r
  if (qrow < S) {
    float rl = (lsum_ > 0.f) ? (1.0f / lsum_) : 0.f;
    #pragma unroll
    for (int dt = 0; dt < 8; dt++) {
      u32 w0 = (u32)f2bf(o[dt][0] * rl) | ((u32)f2bf(o[dt][1] * rl) << 16);
      u32 w1 = (u32)f2bf(o[dt][2] * rl) | ((u32)f2bf(o[dt][3] * rl) << 16);
      *(uint2*)(po + (pbase + qrow) * HDIM + dt * 16 + (g << 2)) = make_uint2(w0, w1);
    }
    if (l < 16) { pm[pbase + qrow] = m_; pl[pbase + qrow] = lsum_; }
  }
}

// ---------------- combine split-K partials (base-2 domain) ----------------
__global__ void k_attn_reduce(const u16* __restrict__ po, const float* __restrict__ pm,
                              const float* __restrict__ pl, u16* __restrict__ attn_out,
                              int S) {
  const int t = blockIdx.x;
  const int h = blockIdx.y;
  const int d = threadIdx.x;   // 128 threads
  float ms[NSPLIT];
  float M = -3.0e38f;
  #pragma unroll
  for (int s = 0; s < NSPLIT; s++) {
    ms[s] = pm[((size_t)h * NSPLIT + s) * S + t];
    M = fmaxf(M, ms[s]);
  }
  float L = 0.f, acc = 0.f;
  #pragma unroll
  for (int s = 0; s < NSPLIT; s++) {
    float wgt = exp2f(ms[s] - M) * pl[((size_t)h * NSPLIT + s) * S + t];
    L += wgt;
    acc += wgt * bf2f(po[(((size_t)h * NSPLIT + s) * S + t) * HDIM + d]);
  }
  attn_out[(size_t)t * MODEL_DIM + h * HDIM + d] = f2bf(acc / L);
}

extern "C" void kernel_launch(void* const* d_in, const int* in_sizes, int n_in,
                              void* d_out, int out_size, void* d_ws, size_t ws_size,
                              hipStream_t stream) {
  (void)n_in; (void)out_size; (void)ws_size;
  const float* x  = (const float*)d_in[0];
  const float* wq = (const float*)d_in[1];
  const float* bq = (const float*)d_in[2];
  const float* wk = (const float*)d_in[3];
  const float* bk = (const float*)d_in[4];
  const float* wv = (const float*)d_in[5];
  const float* bv = (const float*)d_in[6];
  const float* wo = (const float*)d_in[7];
  const float* bo = (const float*)d_in[8];
  const float* gq = (const float*)d_in[9];
  const float* gk = (const float*)d_in[10];
  const float* freqs = (const float*)d_in[11];
  const float* k_cache = (const float*)d_in[12];
  const float* v_cache = (const float*)d_in[13];
  const int* gs  = (const int*)d_in[14];
  const int* csp = (const int*)d_in[15];

  const int S = in_sizes[0] / MODEL_DIM;
  const int CACHE = in_sizes[12] / (NHEADS * HDIM);
  const int KVcap = (CACHE < MAX_ATTN_W) ? CACHE : MAX_ATTN_W;

  char* ws = (char*)d_ws;
  size_t off = 0;
  auto alloc = [&](size_t bytes) {
    char* p = ws + off;
    off += (bytes + 255) & ~(size_t)255;
    return p;
  };
  u16* xb   = (u16*)alloc((size_t)S * MODEL_DIM * 2);
  u16* wqb  = (u16*)alloc((size_t)MODEL_DIM * MODEL_DIM * 2);
  u16* wkb  = (u16*)alloc((size_t)MODEL_DIM * MODEL_DIM * 2);
  u16* wvb  = (u16*)alloc((size_t)MODEL_DIM * MODEL_DIM * 2);
  u16* wob  = (u16*)alloc((size_t)MODEL_DIM * MODEL_DIM * 2);
  float* q_pre = (float*)alloc((size_t)S * MODEL_DIM * 4);
  float* k_pre = (float*)alloc((size_t)S * MODEL_DIM * 4);
  float* v_pre = (float*)alloc((size_t)S * MODEL_DIM * 4);
  u16* rqb   = (u16*)alloc((size_t)NHEADS * S * HDIM * 2);
  u16* K_all = (u16*)alloc((size_t)NHEADS * KVcap * HDIM * 2);
  u16* VT    = (u16*)alloc((size_t)NHEADS * HDIM * KVcap * 2);
  u16* attn_o = (u16*)alloc((size_t)S * MODEL_DIM * 2);
  u16* po    = (u16*)alloc((size_t)NHEADS * NSPLIT * S * HDIM * 2);
  float* pm  = (float*)alloc((size_t)NHEADS * NSPLIT * S * 4);
  float* pl  = (float*)alloc((size_t)NHEADS * NSPLIT * S * 4);

  const int nx4 = S * MODEL_DIM / 4;
  const int nw4 = MODEL_DIM * MODEL_DIM / 4;
  hipLaunchKernelGGL(k_conv_bf16, dim3((nx4 + 255) / 256), dim3(256), 0, stream, x, xb, nx4);
  hipLaunchKernelGGL(k_conv_bf16_w4, dim3((nw4 + 255) / 256, 4), dim3(256), 0, stream,
                     wq, wk, wv, wo, wqb, wkb, wvb, wob, nw4);

  hipLaunchKernelGGL(k_build_kold, dim3(2048), dim3(256), 0, stream, k_cache, K_all, csp, S, KVcap);
  hipLaunchKernelGGL(k_build_vtold, dim3((KVcap + 63) / 64, NHEADS), dim3(256), 0, stream,
                     v_cache, VT, csp, S, KVcap);

  hipLaunchKernelGGL(k_gemm_qkv, dim3((S + 63) / 64, 3 * MODEL_DIM / 64), dim3(256), 0, stream,
                     xb, wqb, wkb, wvb, bq, bk, bv, q_pre, k_pre, v_pre, S, MODEL_DIM, MODEL_DIM);

  hipLaunchKernelGGL(k_norm_rope, dim3(S), dim3(256), 0, stream,
                     q_pre, k_pre, v_pre, gq, gk, freqs, gs, csp, S, KVcap, rqb, K_all, VT);

  hipLaunchKernelGGL(k_attn_split, dim3((S + 63) / 64, NHEADS, NSPLIT), dim3(256), 0, stream,
                     rqb, K_all, VT, po, pm, pl, csp, S, KVcap);

  hipLaunchKernelGGL(k_attn_reduce, dim3(S, NHEADS), dim3(128), 0, stream, po, pm, pl, attn_o, S);

  hipLaunchKernelGGL(k_gemm_bt, dim3((S + 63) / 64, MODEL_DIM / 64), dim3(256), 0, stream,
                     attn_o, wob, bo, (float*)d_out, S, MODEL_DIM, MODEL_DIM);
}

// Round 6
// 326.516 us; speedup vs baseline: 3.1312x; 1.1329x over previous
//
#include <hip/hip_runtime.h>

#define NHEADS 12
#define HDIM 128
#define MODEL_DIM 1536
#define MAX_ATTN_W 13200
#define NSPLIT 12

typedef unsigned short u16;
typedef unsigned int u32;
typedef float f32x4 __attribute__((ext_vector_type(4)));
typedef float f32x16 __attribute__((ext_vector_type(16)));
typedef __bf16 bf16x8 __attribute__((ext_vector_type(8)));

static __device__ __forceinline__ u16 f2bf(float f) {
  union { __bf16 h; u16 u; } cv;
  cv.h = (__bf16)f;
  return cv.u;
}
static __device__ __forceinline__ float bf2f(u16 u) {
  union { u32 u; float f; } cv;
  cv.u = ((u32)u) << 16;
  return cv.f;
}

// ---------------- fp32 -> bf16 convert (single buffer) ----------------
__global__ void k_conv_bf16(const float* __restrict__ src, u16* __restrict__ dst, int n4) {
  int i = blockIdx.x * blockDim.x + threadIdx.x;
  if (i >= n4) return;
  float4 v = ((const float4*)src)[i];
  u32 lo = (u32)f2bf(v.x) | ((u32)f2bf(v.y) << 16);
  u32 hi = (u32)f2bf(v.z) | ((u32)f2bf(v.w) << 16);
  ((uint2*)dst)[i] = make_uint2(lo, hi);
}

// ---------------- fp32 -> bf16 convert, 4 weight matrices in one launch ----------------
__global__ void k_conv_bf16_w4(const float* __restrict__ s0, const float* __restrict__ s1,
                               const float* __restrict__ s2, const float* __restrict__ s3,
                               u16* __restrict__ d0, u16* __restrict__ d1,
                               u16* __restrict__ d2, u16* __restrict__ d3, int n4) {
  int i = blockIdx.x * blockDim.x + threadIdx.x;
  if (i >= n4) return;
  const int which = blockIdx.y;
  const float* src = (which == 0) ? s0 : (which == 1) ? s1 : (which == 2) ? s2 : s3;
  u16* dst = (which == 0) ? d0 : (which == 1) ? d1 : (which == 2) ? d2 : d3;
  float4 v = ((const float4*)src)[i];
  u32 lo = (u32)f2bf(v.x) | ((u32)f2bf(v.y) << 16);
  u32 hi = (u32)f2bf(v.z) | ((u32)f2bf(v.w) << 16);
  ((uint2*)dst)[i] = make_uint2(lo, hi);
}

// ---------------- old cache -> bf16 K window [n][jj][d] (coalesced both sides) ----------------
__global__ void k_build_kold(const float* __restrict__ kc, u16* __restrict__ K_all,
                             const int* __restrict__ csp, int S, int KVcap) {
  const int cs = csp[0];
  const int ce = cs + S;
  int wst = ce - MAX_ATTN_W; if (wst < 0) wst = 0;
  const int oldlen = cs - wst;
  const long per = (long)oldlen * 16;   // 16 chunks of 8 along d
  const long total = per * NHEADS;
  for (long c = blockIdx.x * (long)blockDim.x + threadIdx.x; c < total;
       c += (long)gridDim.x * blockDim.x) {
    int n = (int)(c / per);
    long r = c - (long)n * per;
    int jo = (int)(r >> 4);
    int dc = ((int)r & 15) * 8;
    const float* s = kc + ((size_t)(wst + jo) * NHEADS + n) * HDIM + dc;
    float4 a = *(const float4*)s;
    float4 b = *(const float4*)(s + 4);
    uint4 o;
    o.x = (u32)f2bf(a.x) | ((u32)f2bf(a.y) << 16);
    o.y = (u32)f2bf(a.z) | ((u32)f2bf(a.w) << 16);
    o.z = (u32)f2bf(b.x) | ((u32)f2bf(b.y) << 16);
    o.w = (u32)f2bf(b.z) | ((u32)f2bf(b.w) << 16);
    *(uint4*)(K_all + ((size_t)n * KVcap + jo) * HDIM + dc) = o;
  }
}

// ---------------- old cache -> bf16 V^T window [n][d][jj], LDS tile transpose ----------------
__launch_bounds__(256)
__global__ void k_build_vtold(const float* __restrict__ vc, u16* __restrict__ VT,
                              const int* __restrict__ csp, int S, int KVcap) {
  __shared__ u16 tile[64][130];
  const int cs = csp[0];
  const int ce = cs + S;
  int wst = ce - MAX_ATTN_W; if (wst < 0) wst = 0;
  const int oldlen = cs - wst;
  const int n = blockIdx.y;
  const int j0 = blockIdx.x * 64;
  if (j0 >= oldlen) return;
  const int tid = threadIdx.x;

  #pragma unroll
  for (int i = 0; i < 8; i++) {
    int idx = tid + 256 * i;
    int j = idx >> 5;
    int dc = (idx & 31) * 4;
    float4 v = make_float4(0.f, 0.f, 0.f, 0.f);
    if (j0 + j < oldlen)
      v = *(const float4*)(vc + ((size_t)(wst + j0 + j) * NHEADS + n) * HDIM + dc);
    u32 lo = (u32)f2bf(v.x) | ((u32)f2bf(v.y) << 16);
    u32 hi = (u32)f2bf(v.z) | ((u32)f2bf(v.w) << 16);
    *(u32*)&tile[j][dc] = lo;
    *(u32*)&tile[j][dc + 2] = hi;
  }
  __syncthreads();

  const int d = tid >> 1;
  const int jh = (tid & 1) * 32;
  alignas(16) u16 buf[32];
  #pragma unroll
  for (int j = 0; j < 32; j++) buf[j] = tile[jh + j][d];
  u16* dst = VT + ((size_t)n * HDIM + d) * KVcap + j0 + jh;
  if (j0 + jh + 32 <= oldlen) {
    #pragma unroll
    for (int c = 0; c < 4; c++)
      *(uint4*)(dst + c * 8) = *(const uint4*)&buf[c * 8];
  } else {
    for (int j = 0; j < 32 && j0 + jh + j < oldlen; j++) dst[j] = buf[j];
  }
}

// ---------------- bf16 GEMM: out[m][n] = sum_k A[m][k]*B[n][k] + bias[n] ----------------
__launch_bounds__(256)
__global__ void k_gemm_bt(const u16* __restrict__ A, const u16* __restrict__ B,
                          const float* __restrict__ bias, float* __restrict__ out,
                          int M, int N, int K) {
  __shared__ __align__(16) u16 Al[64][40];
  __shared__ __align__(16) u16 Bl[64][40];
  const int tid = threadIdx.x;
  const int w = tid >> 6, l = tid & 63, l15 = l & 15, g = l >> 4;
  const int wr = w >> 1, wc = w & 1;
  const int m0 = blockIdx.x * 64, n0 = blockIdx.y * 64;
  f32x4 acc[2][2] = {};
  const int row = tid >> 2, colc = (tid & 3) * 8;
  for (int k0 = 0; k0 < K; k0 += 32) {
    __syncthreads();
    uint4 av = make_uint4(0, 0, 0, 0);
    int gm = m0 + row;
    if (gm < M) av = *(const uint4*)(A + (size_t)gm * K + k0 + colc);
    *(uint4*)&Al[row][colc] = av;
    uint4 bv = *(const uint4*)(B + (size_t)(n0 + row) * K + k0 + colc);
    *(uint4*)&Bl[row][colc] = bv;
    __syncthreads();
    bf16x8 af[2], bfr[2];
    #pragma unroll
    for (int mt = 0; mt < 2; mt++) af[mt] = *(const bf16x8*)&Al[wr * 32 + mt * 16 + l15][g * 8];
    #pragma unroll
    for (int nt = 0; nt < 2; nt++) bfr[nt] = *(const bf16x8*)&Bl[wc * 32 + nt * 16 + l15][g * 8];
    #pragma unroll
    for (int mt = 0; mt < 2; mt++)
      #pragma unroll
      for (int nt = 0; nt < 2; nt++)
        acc[mt][nt] = __builtin_amdgcn_mfma_f32_16x16x32_bf16(af[mt], bfr[nt], acc[mt][nt], 0, 0, 0);
  }
  #pragma unroll
  for (int mt = 0; mt < 2; mt++)
    #pragma unroll
    for (int nt = 0; nt < 2; nt++)
      #pragma unroll
      for (int r = 0; r < 4; r++) {
        int mm = m0 + wr * 32 + mt * 16 + (g << 2) + r;
        int nn = n0 + wc * 32 + nt * 16 + l15;
        if (mm < M) out[(size_t)mm * N + nn] = acc[mt][nt][r] + bias[nn];
      }
}

// ---------------- fused QKV GEMM (3 weight matrices, one launch) ----------------
__launch_bounds__(256)
__global__ void k_gemm_qkv(const u16* __restrict__ A,
                           const u16* __restrict__ B0, const u16* __restrict__ B1,
                           const u16* __restrict__ B2,
                           const float* __restrict__ bias0, const float* __restrict__ bias1,
                           const float* __restrict__ bias2,
                           float* __restrict__ o0, float* __restrict__ o1, float* __restrict__ o2,
                           int M, int N, int K) {
  __shared__ __align__(16) u16 Al[64][40];
  __shared__ __align__(16) u16 Bl[64][40];
  const int nblk = N / 64;
  const int which = blockIdx.y / nblk;
  const int n0 = (blockIdx.y % nblk) * 64;
  const u16* B = (which == 0) ? B0 : ((which == 1) ? B1 : B2);
  const float* bias = (which == 0) ? bias0 : ((which == 1) ? bias1 : bias2);
  float* out = (which == 0) ? o0 : ((which == 1) ? o1 : o2);
  const int tid = threadIdx.x;
  const int w = tid >> 6, l = tid & 63, l15 = l & 15, g = l >> 4;
  const int wr = w >> 1, wc = w & 1;
  const int m0 = blockIdx.x * 64;
  f32x4 acc[2][2] = {};
  const int row = tid >> 2, colc = (tid & 3) * 8;
  for (int k0 = 0; k0 < K; k0 += 32) {
    __syncthreads();
    uint4 av = make_uint4(0, 0, 0, 0);
    int gm = m0 + row;
    if (gm < M) av = *(const uint4*)(A + (size_t)gm * K + k0 + colc);
    *(uint4*)&Al[row][colc] = av;
    uint4 bv = *(const uint4*)(B + (size_t)(n0 + row) * K + k0 + colc);
    *(uint4*)&Bl[row][colc] = bv;
    __syncthreads();
    bf16x8 af[2], bfr[2];
    #pragma unroll
    for (int mt = 0; mt < 2; mt++) af[mt] = *(const bf16x8*)&Al[wr * 32 + mt * 16 + l15][g * 8];
    #pragma unroll
    for (int nt = 0; nt < 2; nt++) bfr[nt] = *(const bf16x8*)&Bl[wc * 32 + nt * 16 + l15][g * 8];
    #pragma unroll
    for (int mt = 0; mt < 2; mt++)
      #pragma unroll
      for (int nt = 0; nt < 2; nt++)
        acc[mt][nt] = __builtin_amdgcn_mfma_f32_16x16x32_bf16(af[mt], bfr[nt], acc[mt][nt], 0, 0, 0);
  }
  #pragma unroll
  for (int mt = 0; mt < 2; mt++)
    #pragma unroll
    for (int nt = 0; nt < 2; nt++)
      #pragma unroll
      for (int r = 0; r < 4; r++) {
        int mm = m0 + wr * 32 + mt * 16 + (g << 2) + r;
        int nn = n0 + wc * 32 + nt * 16 + l15;
        if (mm < M) out[(size_t)mm * N + nn] = acc[mt][nt][r] + bias[nn];
      }
}

// ---------------- fused RMSNorm + RoPE + KV-window scatter ----------------
__launch_bounds__(256)
__global__ void k_norm_rope(const float* __restrict__ qp, const float* __restrict__ kp,
                            const float* __restrict__ vp, const float* __restrict__ gq,
                            const float* __restrict__ gk, const float* __restrict__ freqs,
                            const int* __restrict__ gs, const int* __restrict__ csp,
                            int S, int KVcap,
                            u16* __restrict__ rq, u16* __restrict__ K_all,
                            u16* __restrict__ VT) {
  const int t = blockIdx.x;
  const int tid = threadIdx.x;
  const float* q = qp + (size_t)t * MODEL_DIM;
  const float* k = kp + (size_t)t * MODEL_DIM;
  const float* v = vp + (size_t)t * MODEL_DIM;
  float sq = 0.f, sk = 0.f;
  for (int j = tid; j < MODEL_DIM; j += 256) {
    float a = q[j]; sq += a * a;
    float b = k[j]; sk += b * b;
  }
  #pragma unroll
  for (int off = 32; off > 0; off >>= 1) {
    sq += __shfl_down(sq, off, 64);
    sk += __shfl_down(sk, off, 64);
  }
  __shared__ float red[8];
  int wv_ = tid >> 6, l = tid & 63;
  if (l == 0) { red[wv_] = sq; red[4 + wv_] = sk; }
  __syncthreads();
  sq = red[0] + red[1] + red[2] + red[3];
  sk = red[4] + red[5] + red[6] + red[7];
  const float rq_s = rsqrtf(sq * (1.0f / MODEL_DIM) + 1e-6f);
  const float rk_s = rsqrtf(sk * (1.0f / MODEL_DIM) + 1e-6f);

  const int cs = csp[0];
  const int h = gs[1], ww = gs[2];
  const int hw = h * ww;
  const int sf = cs / hw;                 // start_frame
  const int fi = t / hw;
  const int rr = t - fi * hw;
  const int hi = rr / ww;
  const int wi = rr - hi * ww;
  const int ce = cs + S;
  int wst = ce - MAX_ATTN_W; if (wst < 0) wst = 0;
  const int jj = cs + t - wst;

  for (int p = tid; p < NHEADS * 64; p += 256) {
    int n = p >> 6, c = p & 63;
    int pos = (c < 22) ? (sf + fi) : ((c < 43) ? hi : wi);
    float cv = freqs[(pos * 64 + c) * 2];
    float sv = freqs[(pos * 64 + c) * 2 + 1];
    int j0 = n * HDIM + 2 * c;
    float qr = q[j0] * rq_s * gq[j0];
    float qi = q[j0 + 1] * rq_s * gq[j0 + 1];
    u32 oq = (u32)f2bf(qr * cv - qi * sv) | ((u32)f2bf(qr * sv + qi * cv) << 16);
    *(u32*)(rq + ((size_t)n * S + t) * HDIM + 2 * c) = oq;
    float kr = k[j0] * rk_s * gk[j0];
    float ki = k[j0 + 1] * rk_s * gk[j0 + 1];
    u32 ok = (u32)f2bf(kr * cv - ki * sv) | ((u32)f2bf(kr * sv + ki * cv) << 16);
    *(u32*)(K_all + ((size_t)n * KVcap + jj) * HDIM + 2 * c) = ok;
  }
  for (int j = tid; j < MODEL_DIM; j += 256) {
    int n = j >> 7, d = j & 127;
    VT[((size_t)n * HDIM + d) * KVcap + jj] = f2bf(v[j]);
  }
}

// ---------------- flash attention, split-K, 32x32 MFMA + in-register P ----------------
// Swapped QK: S^T = mfma_32x32x16(K, Q): lane l: q = l&31, key offs (r&3)+8*(r>>2)+4*(l>>5).
// Softmax per-lane + one shfl_xor(32). P half-exchange via shfl_xor(32) + cndmask selects
// (validated primitives only). K/V LDS XOR-swizzled ((row&7)<<3 on u16 idx).
__launch_bounds__(256, 2)
__global__ void k_attn_split(const u16* __restrict__ rq, const u16* __restrict__ K_all,
                             const u16* __restrict__ VT,
                             u16* __restrict__ po, float* __restrict__ pm, float* __restrict__ pl,
                             const int* __restrict__ csp, int S, int KVcap) {
  __shared__ __align__(16) u16 Klds[64][128];
  __shared__ __align__(16) u16 Vlds[128][64];

  const int tid = threadIdx.x;
  const int wid = tid >> 6;
  const int l = tid & 63;
  const int l31 = l & 31;
  const int hi = l >> 5;
  const int swz = (l31 & 7) << 3;
  const int head = blockIdx.y;
  const int split = blockIdx.z;
  const int q0 = blockIdx.x * 128;

  const int cs = csp[0];
  const int ce = cs + S;
  int wst = ce - MAX_ATTN_W; if (wst < 0) wst = 0;
  const int KV = ce - wst;
  const int chunk = (((KV + NSPLIT - 1) / NSPLIT) + 63) & ~63;
  const int kstart = split * chunk;
  int kend = kstart + chunk; if (kend > KV) kend = KV;

  const size_t pbase = ((size_t)head * NSPLIT + split) * S;
  const int qrow = q0 + wid * 32 + l31;

  if (kstart >= kend) {
    if (qrow < S && hi == 0) { pm[pbase + qrow] = -3.0e38f; pl[pbase + qrow] = 0.f; }
    return;
  }

  // Q fragments: lane supplies Q[q=qrow][k = ds*16 + hi*8 + i] (B-frag of 32x32x16)
  bf16x8 qf[8];
  if (qrow < S) {
    const u16* qp = rq + ((size_t)head * S + qrow) * HDIM;
    #pragma unroll
    for (int ds = 0; ds < 8; ds++) qf[ds] = *(const bf16x8*)(qp + ds * 16 + hi * 8);
  } else {
    #pragma unroll
    for (int ds = 0; ds < 8; ds++)
      #pragma unroll
      for (int i = 0; i < 8; i++) qf[ds][i] = (__bf16)0.0f;
  }

  f32x16 o[4];
  #pragma unroll
  for (int dt = 0; dt < 4; dt++)
    #pragma unroll
    for (int j = 0; j < 16; j++) o[dt][j] = 0.f;
  float m_ = -3.0e38f, lsum_ = 0.f;

  const u16* Kh = K_all + (size_t)head * KVcap * HDIM;
  const u16* Vh = VT + (size_t)head * HDIM * KVcap;
  const float sc2 = 0.12751744f;   // (1/sqrt(128)) * log2(e)

  uint4 kr[4], vr[4];
  auto load_tile = [&](int key0) {
    #pragma unroll
    for (int i = 0; i < 4; i++) {
      int cid = tid + 256 * i;
      int krow = cid >> 4;
      int gk_ = key0 + krow;
      kr[i] = make_uint4(0, 0, 0, 0);
      if (gk_ < kend) kr[i] = *(const uint4*)(Kh + (size_t)gk_ * HDIM + (cid & 15) * 8);
    }
    #pragma unroll
    for (int i = 0; i < 4; i++) {
      int cid = tid + 256 * i;
      int d = cid >> 3;
      int kc = (cid & 7) * 8;
      const u16* src = Vh + (size_t)d * KVcap + key0 + kc;
      if (key0 + kc + 8 <= kend) {
        vr[i] = *(const uint4*)src;
      } else {
        alignas(16) u16 tmp[8];
        #pragma unroll
        for (int j = 0; j < 8; j++) tmp[j] = (key0 + kc + j < kend) ? src[j] : (u16)0;
        vr[i] = *(const uint4*)tmp;
      }
    }
  };

  const int ntiles = (kend - kstart + 63) >> 6;
  load_tile(kstart);

  for (int t = 0; t < ntiles; t++) {
    const int key0 = kstart + (t << 6);
    __syncthreads();   // previous tile's LDS reads done
    #pragma unroll
    for (int i = 0; i < 4; i++) {
      int cid = tid + 256 * i;
      int krow = cid >> 4;
      *(uint4*)&Klds[krow][((cid & 15) * 8) ^ ((krow & 7) << 3)] = kr[i];
    }
    #pragma unroll
    for (int i = 0; i < 4; i++) {
      int cid = tid + 256 * i;
      int d = cid >> 3;
      *(uint4*)&Vlds[d][((cid & 7) * 8) ^ ((d & 7) << 3)] = vr[i];
    }
    if (t + 1 < ntiles) load_tile(key0 + 64);   // prefetch overlaps compute below
    __syncthreads();

    // QK^T swapped: s[kt] = S^T over keys [key0+32kt, +32), q = l31
    f32x16 s[2];
    #pragma unroll
    for (int kt = 0; kt < 2; kt++) {
      #pragma unroll
      for (int j = 0; j < 16; j++) s[kt][j] = 0.f;
      #pragma unroll
      for (int ds = 0; ds < 8; ds++) {
        bf16x8 kf = *(const bf16x8*)&Klds[kt * 32 + l31][(ds * 16 + hi * 8) ^ swz];
        s[kt] = __builtin_amdgcn_mfma_f32_32x32x16_bf16(kf, qf[ds], s[kt], 0, 0, 0);
      }
    }

    // mask + scale (base-2); in-lane max over 32, one cross-half reduce
    float tm = -3.0e38f;
    #pragma unroll
    for (int kt = 0; kt < 2; kt++) {
      const int rem = kend - key0 - kt * 32;
      #pragma unroll
      for (int r = 0; r < 16; r++) {
        const int off = (r & 3) + 8 * (r >> 2) + 4 * hi;
        float v = s[kt][r] * sc2;
        v = (off < rem) ? v : -3.0e38f;
        s[kt][r] = v;
        tm = fmaxf(tm, v);
      }
    }
    tm = fmaxf(tm, __shfl_xor(tm, 32, 64));
    float nm = fmaxf(m_, tm);
    float alpha = exp2f(m_ - nm);
    m_ = nm;

    float rs = 0.f;
    u32 w[2][8];
    #pragma unroll
    for (int kt = 0; kt < 2; kt++)
      #pragma unroll
      for (int j = 0; j < 8; j++) {
        float p0 = exp2f(s[kt][2 * j] - m_);
        float p1 = exp2f(s[kt][2 * j + 1] - m_);
        rs += p0 + p1;
        w[kt][j] = (u32)f2bf(p0) | ((u32)f2bf(p1) << 16);
      }
    rs += __shfl_xor(rs, 32, 64);
    lsum_ = lsum_ * alpha + rs;

    // assemble PV B-frags: half-exchange via shfl_xor(32), then per-half selects.
    // lane(hi) word layout of w[kt]: hi=0 -> {0,1},{2,3},{8,9},{10,11},{16,17},{18,19},{24,25},{26,27}
    //                                hi=1 -> {4,5},{6,7},{12,13},{14,15},{20,21},{22,23},{28,29},{30,31}
    // pf[kt][mm][i] needs key offset mm*16 + hi*8 + i.
    union { u32 u[4]; bf16x8 v; } pf[2][2];
    #pragma unroll
    for (int kt = 0; kt < 2; kt++) {
      u32 xw[8];
      #pragma unroll
      for (int j = 0; j < 8; j++) xw[j] = __shfl_xor(w[kt][j], 32, 64);
      pf[kt][0].u[0] = hi ? xw[2]    : w[kt][0];
      pf[kt][0].u[1] = hi ? xw[3]    : w[kt][1];
      pf[kt][0].u[2] = hi ? w[kt][2] : xw[0];
      pf[kt][0].u[3] = hi ? w[kt][3] : xw[1];
      pf[kt][1].u[0] = hi ? xw[6]    : w[kt][4];
      pf[kt][1].u[1] = hi ? xw[7]    : w[kt][5];
      pf[kt][1].u[2] = hi ? w[kt][6] : xw[4];
      pf[kt][1].u[3] = hi ? w[kt][7] : xw[5];
    }

    #pragma unroll
    for (int dt = 0; dt < 4; dt++)
      #pragma unroll
      for (int j = 0; j < 16; j++) o[dt][j] *= alpha;

    // PV swapped: O^T[d][q] += V^T[d][key] * P[key][q]
    #pragma unroll
    for (int dt = 0; dt < 4; dt++) {
      #pragma unroll
      for (int kt = 0; kt < 2; kt++)
        #pragma unroll
        for (int mm = 0; mm < 2; mm++) {
          bf16x8 vf = *(const bf16x8*)&Vlds[dt * 32 + l31][(kt * 32 + mm * 16 + hi * 8) ^ swz];
          o[dt] = __builtin_amdgcn_mfma_f32_32x32x16_bf16(vf, pf[kt][mm].v, o[dt], 0, 0, 0);
        }
    }
  }

  // epilogue: q = qrow; d = dt*32 + 8*jj + (reg&3) + 4*hi
  if (qrow < S) {
    float rl = (lsum_ > 0.f) ? (1.0f / lsum_) : 0.f;
    u16* dst = po + (pbase + qrow) * HDIM;
    #pragma unroll
    for (int dt = 0; dt < 4; dt++)
      #pragma unroll
      for (int jj = 0; jj < 4; jj++) {
        u32 w0 = (u32)f2bf(o[dt][4 * jj] * rl) | ((u32)f2bf(o[dt][4 * jj + 1] * rl) << 16);
        u32 w1 = (u32)f2bf(o[dt][4 * jj + 2] * rl) | ((u32)f2bf(o[dt][4 * jj + 3] * rl) << 16);
        *(uint2*)(dst + dt * 32 + 8 * jj + 4 * hi) = make_uint2(w0, w1);
      }
    if (hi == 0) { pm[pbase + qrow] = m_; pl[pbase + qrow] = lsum_; }
  }
}

// ---------------- combine split-K partials (base-2 domain) ----------------
__global__ void k_attn_reduce(const u16* __restrict__ po, const float* __restrict__ pm,
                              const float* __restrict__ pl, u16* __restrict__ attn_out,
                              int S) {
  const int t = blockIdx.x;
  const int h = blockIdx.y;
  const int d = threadIdx.x;   // 128 threads
  float ms[NSPLIT];
  float M = -3.0e38f;
  #pragma unroll
  for (int s = 0; s < NSPLIT; s++) {
    ms[s] = pm[((size_t)h * NSPLIT + s) * S + t];
    M = fmaxf(M, ms[s]);
  }
  float L = 0.f, acc = 0.f;
  #pragma unroll
  for (int s = 0; s < NSPLIT; s++) {
    float wgt = exp2f(ms[s] - M) * pl[((size_t)h * NSPLIT + s) * S + t];
    L += wgt;
    acc += wgt * bf2f(po[(((size_t)h * NSPLIT + s) * S + t) * HDIM + d]);
  }
  attn_out[(size_t)t * MODEL_DIM + h * HDIM + d] = f2bf(acc / L);
}

extern "C" void kernel_launch(void* const* d_in, const int* in_sizes, int n_in,
                              void* d_out, int out_size, void* d_ws, size_t ws_size,
                              hipStream_t stream) {
  (void)n_in; (void)out_size; (void)ws_size;
  const float* x  = (const float*)d_in[0];
  const float* wq = (const float*)d_in[1];
  const float* bq = (const float*)d_in[2];
  const float* wk = (const float*)d_in[3];
  const float* bk = (const float*)d_in[4];
  const float* wv = (const float*)d_in[5];
  const float* bv = (const float*)d_in[6];
  const float* wo = (const float*)d_in[7];
  const float* bo = (const float*)d_in[8];
  const float* gq = (const float*)d_in[9];
  const float* gk = (const float*)d_in[10];
  const float* freqs = (const float*)d_in[11];
  const float* k_cache = (const float*)d_in[12];
  const float* v_cache = (const float*)d_in[13];
  const int* gs  = (const int*)d_in[14];
  const int* csp = (const int*)d_in[15];

  const int S = in_sizes[0] / MODEL_DIM;
  const int CACHE = in_sizes[12] / (NHEADS * HDIM);
  const int KVcap = (CACHE < MAX_ATTN_W) ? CACHE : MAX_ATTN_W;

  char* ws = (char*)d_ws;
  size_t off = 0;
  auto alloc = [&](size_t bytes) {
    char* p = ws + off;
    off += (bytes + 255) & ~(size_t)255;
    return p;
  };
  u16* xb   = (u16*)alloc((size_t)S * MODEL_DIM * 2);
  u16* wqb  = (u16*)alloc((size_t)MODEL_DIM * MODEL_DIM * 2);
  u16* wkb  = (u16*)alloc((size_t)MODEL_DIM * MODEL_DIM * 2);
  u16* wvb  = (u16*)alloc((size_t)MODEL_DIM * MODEL_DIM * 2);
  u16* wob  = (u16*)alloc((size_t)MODEL_DIM * MODEL_DIM * 2);
  float* q_pre = (float*)alloc((size_t)S * MODEL_DIM * 4);
  float* k_pre = (float*)alloc((size_t)S * MODEL_DIM * 4);
  float* v_pre = (float*)alloc((size_t)S * MODEL_DIM * 4);
  u16* rqb   = (u16*)alloc((size_t)NHEADS * S * HDIM * 2);
  u16* K_all = (u16*)alloc((size_t)NHEADS * KVcap * HDIM * 2);
  u16* VT    = (u16*)alloc((size_t)NHEADS * HDIM * KVcap * 2);
  u16* attn_o = (u16*)alloc((size_t)S * MODEL_DIM * 2);
  u16* po    = (u16*)alloc((size_t)NHEADS * NSPLIT * S * HDIM * 2);
  float* pm  = (float*)alloc((size_t)NHEADS * NSPLIT * S * 4);
  float* pl  = (float*)alloc((size_t)NHEADS * NSPLIT * S * 4);

  const int nx4 = S * MODEL_DIM / 4;
  const int nw4 = MODEL_DIM * MODEL_DIM / 4;
  hipLaunchKernelGGL(k_conv_bf16, dim3((nx4 + 255) / 256), dim3(256), 0, stream, x, xb, nx4);
  hipLaunchKernelGGL(k_conv_bf16_w4, dim3((nw4 + 255) / 256, 4), dim3(256), 0, stream,
                     wq, wk, wv, wo, wqb, wkb, wvb, wob, nw4);

  hipLaunchKernelGGL(k_build_kold, dim3(2048), dim3(256), 0, stream, k_cache, K_all, csp, S, KVcap);
  hipLaunchKernelGGL(k_build_vtold, dim3((KVcap + 63) / 64, NHEADS), dim3(256), 0, stream,
                     v_cache, VT, csp, S, KVcap);

  hipLaunchKernelGGL(k_gemm_qkv, dim3((S + 63) / 64, 3 * MODEL_DIM / 64), dim3(256), 0, stream,
                     xb, wqb, wkb, wvb, bq, bk, bv, q_pre, k_pre, v_pre, S, MODEL_DIM, MODEL_DIM);

  hipLaunchKernelGGL(k_norm_rope, dim3(S), dim3(256), 0, stream,
                     q_pre, k_pre, v_pre, gq, gk, freqs, gs, csp, S, KVcap, rqb, K_all, VT);

  hipLaunchKernelGGL(k_attn_split, dim3((S + 127) / 128, NHEADS, NSPLIT), dim3(256), 0, stream,
                     rqb, K_all, VT, po, pm, pl, csp, S, KVcap);

  hipLaunchKernelGGL(k_attn_reduce, dim3(S, NHEADS), dim3(128), 0, stream, po, pm, pl, attn_o, S);

  hipLaunchKernelGGL(k_gemm_bt, dim3((S + 63) / 64, MODEL_DIM / 64), dim3(256), 0, stream,
                     attn_o, wob, bo, (float*)d_out, S, MODEL_DIM, MODEL_DIM);
}